// Round 8
// baseline (72.120 us; speedup 1.0000x reference)
//
#include <hip/hip_runtime.h>
#include <hip/hip_fp16.h>
#include <math.h>

#define Bb 2
#define Hh 8
#define Tt 4096
#define Kk 128
#define Vv 128
#define Ss 128
#define Cc 32
#define BH (Bb*Hh)
#define SCALE 0.08838834764831845f  /* 1/sqrt(128) */

// ---- workspace layout ----
#define OFF_LFACC  0                               // BH*Tt
#define OFF_LFLAST (OFF_LFACC + BH*Tt)             // BH*Cc
#define OFF_MINTRA (OFF_LFLAST + BH*Cc)
#define OFF_MPREV  (OFF_MINTRA + BH*Cc)
#define OFF_E1     (OFF_MPREV + BH*Cc)
#define OFF_E2     (OFF_E1 + BH*Cc)
#define OFF_KSUM   (OFF_E2 + BH*Cc)                // BH*Cc*Kk (fp32, becomes n_prev)
#define OFF_KVH    (OFF_KSUM + BH*Cc*Kk)           // fp16 kv^T [blk][v][k] (-> c_prev^T)

typedef _Float16 f16x8 __attribute__((ext_vector_type(8)));
typedef _Float16 f16x4 __attribute__((ext_vector_type(4)));
typedef _Float16 f16x2 __attribute__((ext_vector_type(2)));
typedef float f32x4 __attribute__((ext_vector_type(4)));

union U2 { f16x2 h; unsigned u; };
union U8 { f16x8 v; unsigned u[4]; };

// ---------------------------------------------------------------------------
// Kernel 1: fused gates + MFMA kv^T (fp16) + ksum. 512 threads, 8 waves.
// Rep-0 k/v staging loads hoisted ABOVE the gates phase (issue-early, T14).
// ---------------------------------------------------------------------------
__global__ __launch_bounds__(512, 4) void k_kvg(const float* __restrict__ ig,
                                                const float* __restrict__ fg,
                                                const float* __restrict__ kg,
                                                const float* __restrict__ vg,
                                                float* __restrict__ ws) {
    __shared__ _Float16 Kt[Ss * Ss];   // (g*K)^T [kidx][t], swizzled
    __shared__ _Float16 Vt[Ss * Ss];   // V^T [vidx][t], swizzled
    __shared__ float sfg[Ss];
    __shared__ float scomb[4];

    int blk = blockIdx.x;
    int bh = blk >> 5;
    int c  = blk & 31;
    int tid = threadIdx.x;
    int lane = tid & 63;
    int w = tid >> 6;
    int l15 = lane & 15;
    int g = lane >> 4;

    const float* kb = kg + ((size_t)bh * Tt + (size_t)c * Ss) * Kk;
    const float* vb = vg + ((size_t)bh * Tt + (size_t)c * Ss) * Vv;

    // ---- hoisted rep-0 staging loads (latency hides under gates) ----
    int c0a = (tid & 31) * 4;
    int t0a = (tid >> 5) * 4;
    const float* ksrcA = kb + (size_t)t0a * Kk + c0a;
    const float* vsrcA = vb + (size_t)t0a * Vv + c0a;
    float4 kA0 = *(const float4*)(ksrcA);
    float4 kA1 = *(const float4*)(ksrcA + Kk);
    float4 kA2 = *(const float4*)(ksrcA + 2 * Kk);
    float4 kA3 = *(const float4*)(ksrcA + 3 * Kk);
    float4 vA0 = *(const float4*)(vsrcA);
    float4 vA1 = *(const float4*)(vsrcA + Vv);
    float4 vA2 = *(const float4*)(vsrcA + 2 * Vv);
    float4 vA3 = *(const float4*)(vsrcA + 3 * Vv);

    // ---- gates (threads 0..127, shfl-based scan) ----
    bool p0 = tid < Ss;
    int lane64 = tid & 63;
    int wv = (tid >> 6) & 1;
    int gidx = bh * Tt + c * Ss + tid;
    float lfacc = 0.f, fwd = 0.f;
    if (p0) {
        float x  = fg[gidx];
        lfacc = fminf(x, 0.f) - log1pf(__expf(-fabsf(x)));
        for (int off = 1; off < 64; off <<= 1) {
            float o = __shfl_up(lfacc, off);
            if (lane64 >= off) lfacc += o;
        }
        if (lane64 == 63) scomb[wv] = lfacc;
    }
    __syncthreads();
    if (p0) {
        float tot0 = scomb[0];
        if (wv == 1) lfacc += tot0;
        float lflast = tot0 + scomb[1];
        fwd = ig[gidx] + lflast - lfacc;
        float mx = fwd;
        for (int off = 32; off; off >>= 1) mx = fmaxf(mx, __shfl_xor(mx, off));
        if (lane64 == 0) scomb[2 + wv] = mx;
    }
    __syncthreads();
    if (p0) {
        float mi = fmaxf(scomb[2], scomb[3]);
        sfg[tid] = __expf(fwd - mi);
        ws[OFF_LFACC + gidx] = lfacc;
        if (tid == 0) {
            ws[OFF_LFLAST + blk] = scomb[0] + scomb[1];
            ws[OFF_MINTRA + blk] = mi;
        }
    }
    __syncthreads();

    // ---- stage rep0 (from hoisted regs) ----
    {
        float g0 = sfg[t0a], g1 = sfg[t0a + 1], g2 = sfg[t0a + 2], g3 = sfg[t0a + 3];
#pragma unroll
        for (int jc = 0; jc < 4; jc++) {
            float ke0 = (jc == 0 ? kA0.x : jc == 1 ? kA0.y : jc == 2 ? kA0.z : kA0.w);
            float ke1 = (jc == 0 ? kA1.x : jc == 1 ? kA1.y : jc == 2 ? kA1.z : kA1.w);
            float ke2 = (jc == 0 ? kA2.x : jc == 1 ? kA2.y : jc == 2 ? kA2.z : kA2.w);
            float ke3 = (jc == 0 ? kA3.x : jc == 1 ? kA3.y : jc == 2 ? kA3.z : kA3.w);
            float ve0 = (jc == 0 ? vA0.x : jc == 1 ? vA0.y : jc == 2 ? vA0.z : vA0.w);
            float ve1 = (jc == 0 ? vA1.x : jc == 1 ? vA1.y : jc == 2 ? vA1.z : vA1.w);
            float ve2 = (jc == 0 ? vA2.x : jc == 1 ? vA2.y : jc == 2 ? vA2.z : vA2.w);
            float ve3 = (jc == 0 ? vA3.x : jc == 1 ? vA3.y : jc == 2 ? vA3.z : vA3.w);
            int row = c0a + jc;
            int col = t0a ^ ((row & 15) << 3);
            f16x4 kc = { (_Float16)(ke0 * g0), (_Float16)(ke1 * g1),
                         (_Float16)(ke2 * g2), (_Float16)(ke3 * g3) };
            f16x4 vc = { (_Float16)ve0, (_Float16)ve1, (_Float16)ve2, (_Float16)ve3 };
            *(f16x4*)&Kt[row * Ss + col] = kc;
            *(f16x4*)&Vt[row * Ss + col] = vc;
        }
    }
    // ---- stage rep1 (load now) ----
    {
        int tau = tid + 512;
        int c0 = (tau & 31) * 4;
        int t0 = (tau >> 5) * 4;
        const float* ksrc = kb + (size_t)t0 * Kk + c0;
        const float* vsrc = vb + (size_t)t0 * Vv + c0;
        float4 k0 = *(const float4*)(ksrc);
        float4 k1 = *(const float4*)(ksrc + Kk);
        float4 k2 = *(const float4*)(ksrc + 2 * Kk);
        float4 k3 = *(const float4*)(ksrc + 3 * Kk);
        float4 v0 = *(const float4*)(vsrc);
        float4 v1 = *(const float4*)(vsrc + Vv);
        float4 v2 = *(const float4*)(vsrc + 2 * Vv);
        float4 v3 = *(const float4*)(vsrc + 3 * Vv);
        float g0 = sfg[t0], g1 = sfg[t0 + 1], g2 = sfg[t0 + 2], g3 = sfg[t0 + 3];
#pragma unroll
        for (int jc = 0; jc < 4; jc++) {
            float ke0 = (jc == 0 ? k0.x : jc == 1 ? k0.y : jc == 2 ? k0.z : k0.w);
            float ke1 = (jc == 0 ? k1.x : jc == 1 ? k1.y : jc == 2 ? k1.z : k1.w);
            float ke2 = (jc == 0 ? k2.x : jc == 1 ? k2.y : jc == 2 ? k2.z : k2.w);
            float ke3 = (jc == 0 ? k3.x : jc == 1 ? k3.y : jc == 2 ? k3.z : k3.w);
            float ve0 = (jc == 0 ? v0.x : jc == 1 ? v0.y : jc == 2 ? v0.z : v0.w);
            float ve1 = (jc == 0 ? v1.x : jc == 1 ? v1.y : jc == 2 ? v1.z : v1.w);
            float ve2 = (jc == 0 ? v2.x : jc == 1 ? v2.y : jc == 2 ? v2.z : v2.w);
            float ve3 = (jc == 0 ? v3.x : jc == 1 ? v3.y : jc == 2 ? v3.z : v3.w);
            int row = c0 + jc;
            int col = t0 ^ ((row & 15) << 3);
            f16x4 kc = { (_Float16)(ke0 * g0), (_Float16)(ke1 * g1),
                         (_Float16)(ke2 * g2), (_Float16)(ke3 * g3) };
            f16x4 vc = { (_Float16)ve0, (_Float16)ve1, (_Float16)ve2, (_Float16)ve3 };
            *(f16x4*)&Kt[row * Ss + col] = kc;
            *(f16x4*)&Vt[row * Ss + col] = vc;
        }
    }
    __syncthreads();

    // ---- ksum: per-row reduction of Kt (threads 0..127) ----
    if (tid < Ss) {
        int sw = (tid & 15) << 3;
        float s = 0.f;
#pragma unroll
        for (int i = 0; i < 16; i++) {
            f16x8 ld = *(const f16x8*)&Kt[tid * Ss + ((8 * i) ^ sw)];
#pragma unroll
            for (int e = 0; e < 8; e++) s += (float)ld[e];
        }
        ws[OFF_KSUM + (size_t)blk * Kk + tid] = s;
    }

    // ---- MFMA (swapped): wave w -> vidx band [16w, 16w+16) ----
    const int band = w * 16;
    const int swt = l15 << 3;
    f16x8 af[4];
#pragma unroll
    for (int kk = 0; kk < 4; kk++)
        af[kk] = *(const f16x8*)&Vt[(band + l15) * Ss + ((kk * 32 + g * 8) ^ swt)];

    f32x4 acc[8];
#pragma unroll
    for (int kj = 0; kj < 8; kj++) acc[kj] = (f32x4){0.f, 0.f, 0.f, 0.f};

#pragma unroll
    for (int kj = 0; kj < 8; kj++) {
        int kr = kj * 16 + l15;
#pragma unroll
        for (int kk = 0; kk < 4; kk++) {
            f16x8 bv = *(const f16x8*)&Kt[kr * Ss + ((kk * 32 + g * 8) ^ swt)];
            acc[kj] = __builtin_amdgcn_mfma_f32_16x16x32_f16(af[kk], bv, acc[kj], 0, 0, 0);
        }
    }

    _Float16* dst = (_Float16*)(ws + OFF_KVH) + (size_t)blk * Kk * Vv;
#pragma unroll
    for (int kj = 0; kj < 8; kj++)
#pragma unroll
        for (int r = 0; r < 4; r++)
            dst[(size_t)(band + 4 * g + r) * Kk + kj * 16 + l15] = (_Float16)acc[kj][r];
}

// ---------------------------------------------------------------------------
// Kernel 2a: scan coefficients — fully parallel (reference quirk: m never
// updates, so every (bh,c) is independent). 1 block, 512 threads.
// ---------------------------------------------------------------------------
__global__ __launch_bounds__(512) void k_scan_coef(const float* __restrict__ m0,
                                                   float* __restrict__ ws) {
    int t = threadIdx.x;             // t == blk == bh*Cc + c
    int bh = t >> 5;
    const float m = m0[bh];
    float lfl = ws[OFF_LFLAST + t];
    float mi  = ws[OFF_MINTRA + t];
    float mn  = fmaxf(lfl + m, mi);
    ws[OFF_MPREV + t] = m;
    ws[OFF_E1 + t] = __expf(lfl + m - mn);
    ws[OFF_E2 + t] = __expf(mi - mn);
}

// ---------------------------------------------------------------------------
// Kernel 2b: scan application with depth-2 prefetch (the 32-step dependent
// load chain was latency-exposed). 128-thr blocks -> 1040 blocks.
// ---------------------------------------------------------------------------
__global__ __launch_bounds__(128) void k_scan_apply(const float* __restrict__ C0,
                                                    const float* __restrict__ n0,
                                                    float* __restrict__ ws) {
    const int NC2 = BH * Kk * Vv / 2;     // 131072 f16x2 elements
    int gid = blockIdx.x * 128 + threadIdx.x;
    if (gid < NC2) {
        int bh = gid >> 13;
        int i  = gid & 8191;
        int v  = i >> 6;
        int k2 = (i & 63) << 1;
        float st0 = C0[(size_t)bh * Kk * Vv + (size_t)k2 * Vv + v];
        float st1 = C0[(size_t)bh * Kk * Vv + (size_t)(k2 + 1) * Vv + v];
        f16x2* base = (f16x2*)((_Float16*)(ws + OFF_KVH) +
                               (size_t)bh * Cc * Kk * Vv + (size_t)v * Kk + k2);
        const float* e1p = ws + OFF_E1 + bh * Cc;
        const float* e2p = ws + OFF_E2 + bh * Cc;
        const size_t stride = Kk * Vv / 2;
        f16x2 cur = base[0];
        f16x2 nxt = base[stride];
#pragma unroll
        for (int c = 0; c < Cc; c++) {
            f16x2 n2 = (c + 2 < Cc) ? base[(size_t)(c + 2) * stride]
                                    : (f16x2){(_Float16)0.f, (_Float16)0.f};
            f16x2 o = { (_Float16)st0, (_Float16)st1 };
            base[(size_t)c * stride] = o;          // c_prev^T for chunk c
            float e1 = e1p[c], e2 = e2p[c];
            st0 = st0 * e1 + (float)cur[0] * e2;
            st1 = st1 * e1 + (float)cur[1] * e2;
            cur = nxt; nxt = n2;
        }
    } else if (gid < NC2 + BH * Kk) {
        int g2 = gid - NC2;
        int bh = g2 / Kk;
        float st = n0[g2];
        float* base = ws + OFF_KSUM + (size_t)bh * Cc * Kk + (g2 % Kk);
        const float* e1p = ws + OFF_E1 + bh * Cc;
        const float* e2p = ws + OFF_E2 + bh * Cc;
        float cur = base[0];
        float nxt = base[Kk];
#pragma unroll
        for (int c = 0; c < Cc; c++) {
            float n2 = (c + 2 < Cc) ? base[(size_t)(c + 2) * Kk] : 0.f;
            float kvv = cur;
            base[(size_t)c * Kk] = st;             // n_prev for chunk c
            st = st * e1p[c] + kvv * e2p[c];
            cur = nxt; nxt = n2;
        }
    }
}

// ---------------------------------------------------------------------------
// Kernel 3 (v3): swapped-QK^T, in-register P — Mb LDS eliminated.
// mfma(A=K_rows, B=Q) -> lane holds P[s=S0+l15][t=16*tj+4g+r]. Gating,
// masking (only tj==w), row-sum (shfl) all lane-local. P->PV-A-frag via
// cross-g shfl exchange of packed fp16 pairs. LDS ~36KB -> 3+ blocks/CU.
// ---------------------------------------------------------------------------
__global__ __launch_bounds__(512, 6) void k_out_mfma(const float* __restrict__ qg,
                                                     const float* __restrict__ kg,
                                                     const float* __restrict__ vg,
                                                     const float* __restrict__ ig,
                                                     float* __restrict__ ws,
                                                     float* __restrict__ out) {
    __shared__ _Float16 Xb[Ss * Kk];    // K [t][k] then V^T [v][t], swizzled
    __shared__ float sbt[Ss], sas[Ss], siw[Ss], smn[Ss], slfa[Ss], snp[Ss];
    __shared__ float scomb[2];

    int blk = blockIdx.x;
    int bh = blk >> 5;
    int c  = blk & 31;
    int tid = threadIdx.x;
    int lane = tid & 63;
    int w = tid >> 6;                   // wave id 0..7; owns s in [16w,16w+16)
    int l15 = lane & 15;
    int g = lane >> 4;                  // 0..3
    const int S0 = w * 16;
    const int swt = (l15 & 7) << 3;

    const size_t rowbase = (size_t)bh * Tt + (size_t)c * Ss;
    const float* qp = qg + rowbase * Kk;
    const float* kp = kg + rowbase * Kk;
    const float* vp = vg + rowbase * Vv;
    const float* nprev = ws + OFF_KSUM + (size_t)blk * Kk;
    const _Float16* cprevT = (const _Float16*)(ws + OFF_KVH) + (size_t)blk * Kk * Vv;
    const float m_prev = ws[OFF_MPREV + blk];

    // ---- issue K staging + Q loads early ----
    int tK  = tid >> 2;
    int khK = (tid & 3) * 32;
    const float* ksrc = kp + (size_t)tK * Kk + khK;
    float4 kreg[8];
#pragma unroll
    for (int i = 0; i < 8; i++) kreg[i] = *(const float4*)&ksrc[4 * i];

    f16x8 qf[4];
#pragma unroll
    for (int kk = 0; kk < 4; kk++) {
        const float* p = qp + (size_t)(S0 + l15) * Kk + kk * 32 + g * 8;
        float4 a = *(const float4*)p;
        float4 b = *(const float4*)(p + 4);
        f16x8 r;
        r[0]=(_Float16)a.x; r[1]=(_Float16)a.y; r[2]=(_Float16)a.z; r[3]=(_Float16)a.w;
        r[4]=(_Float16)b.x; r[5]=(_Float16)b.y; r[6]=(_Float16)b.z; r[7]=(_Float16)b.w;
        qf[kk] = r;
    }

    // ---- phase 0 part 1: bt + prefix max (threads 0..127) ----
    bool p0 = tid < Ss;
    int lane64 = tid & 63;
    int wv = (tid >> 6) & 1;
    float pm = 0.f;
    if (p0) {
        float lfa = ws[OFF_LFACC + bh * Tt + c * Ss + tid];
        float bt = ig[bh * Tt + c * Ss + tid] - lfa;
        sbt[tid] = bt;
        slfa[tid] = lfa;
        snp[tid] = nprev[tid];
        pm = bt;
        for (int off = 1; off < 64; off <<= 1) {
            float o = __shfl_up(pm, off);
            if (lane64 >= off) pm = fmaxf(pm, o);
        }
        if (lane64 == 63) scomb[wv] = pm;
    }
    // ---- write K staging (hoisted regs -> LDS) ----
    {
        int sw = (tK & 7) << 3;
#pragma unroll
        for (int i = 0; i < 8; i++) {
            int col = (khK + 4 * i) ^ sw;
            f16x4 s4 = { (_Float16)kreg[i].x, (_Float16)kreg[i].y,
                         (_Float16)kreg[i].z, (_Float16)kreg[i].w };
            *(f16x4*)&Xb[tK * Kk + col] = s4;
        }
    }
    __syncthreads();   // barrier A: Xb(K), sbt/slfa/snp/scomb ready

    if (p0) {
        if (wv == 1) pm = fmaxf(pm, scomb[0]);
        float mx = fmaxf(pm, m_prev);
        sas[tid] = -mx;
        siw[tid] = SCALE * __expf(m_prev - mx);
    }
    // intern raw dot: q[s].n_prev, s = S0+l15 (lane-local after reduce)
    float dotq = 0.f;
#pragma unroll
    for (int kk = 0; kk < 4; kk++)
#pragma unroll
        for (int e = 0; e < 8; e++)
            dotq += (float)qf[kk][e] * snp[kk * 32 + g * 8 + e];
    dotq += __shfl_xor(dotq, 16);
    dotq += __shfl_xor(dotq, 32);
    __syncthreads();   // barrier B: sas/siw ready

    const float as_s = sas[S0 + l15];
    const float iw_s = siw[S0 + l15];
    const float lfa_s = slfa[S0 + l15];

    // ---- swapped QK^T: lane gets P[s=S0+l15][t=16tj+4g+r] ----
    unsigned plo[8] = {0,0,0,0,0,0,0,0};
    unsigned phi[8] = {0,0,0,0,0,0,0,0};
    float rs = 0.f;
#pragma unroll
    for (int tj = 0; tj < 8; tj++) {
        if (tj <= w) {
            int trow = tj * 16 + l15;
            f16x8 bfr[4];
#pragma unroll
            for (int kk = 0; kk < 4; kk++)
                bfr[kk] = *(const f16x8*)&Xb[trow * Kk + ((kk * 32 + g * 8) ^ swt)];
            f32x4 acc = {0.f, 0.f, 0.f, 0.f};
#pragma unroll
            for (int kk = 0; kk < 4; kk++)
                acc = __builtin_amdgcn_mfma_f32_16x16x32_f16(bfr[kk], qf[kk], acc, 0, 0, 0);
            float vals[4];
#pragma unroll
            for (int r = 0; r < 4; r++) {
                int t = tj * 16 + 4 * g + r;
                float btv = sbt[t];
                float val = acc[r] * SCALE * __expf(as_s + btv);
                if (tj == w && (4 * g + r) > l15) val = 0.f;   // causal mask
                rs += val;
                vals[r] = val;
            }
            U2 lo, hi;
            lo.h = (f16x2){ (_Float16)vals[0], (_Float16)vals[1] };
            hi.h = (f16x2){ (_Float16)vals[2], (_Float16)vals[3] };
            plo[tj] = lo.u;
            phi[tj] = hi.u;
        }
    }
    // row sum across g-groups -> full sum for s = S0+l15
    rs += __shfl_xor(rs, 16);
    rs += __shfl_xor(rs, 32);
    // M_norm for own s
    {
        float engs = __expf(as_s - lfa_s);          // exp(-(lfa+mx))
        float mn = fmaxf(fabsf(rs + dotq * iw_s), engs);
        if (g == 0) smn[S0 + l15] = mn;
    }
    __syncthreads();   // barrier C: all QK^T reads of Xb done; smn written

    // ---- stage V^T into Xb (4x4 register transpose) ----
#pragma unroll
    for (int rep = 0; rep < 2; rep++) {
        int tau = tid + rep * 512;
        int v0 = (tau & 31) * 4;
        int t0 = (tau >> 5) * 4;
        const float* vsrc = vp + (size_t)t0 * Vv + v0;
        float4 a0 = *(const float4*)(vsrc);
        float4 a1 = *(const float4*)(vsrc + Vv);
        float4 a2 = *(const float4*)(vsrc + 2 * Vv);
        float4 a3 = *(const float4*)(vsrc + 3 * Vv);
#pragma unroll
        for (int jc = 0; jc < 4; jc++) {
            float e0 = (jc == 0 ? a0.x : jc == 1 ? a0.y : jc == 2 ? a0.z : a0.w);
            float e1 = (jc == 0 ? a1.x : jc == 1 ? a1.y : jc == 2 ? a1.z : a1.w);
            float e2 = (jc == 0 ? a2.x : jc == 1 ? a2.y : jc == 2 ? a2.z : a2.w);
            float e3 = (jc == 0 ? a3.x : jc == 1 ? a3.y : jc == 2 ? a3.z : a3.w);
            int row = v0 + jc;
            int col = t0 ^ ((row & 7) << 3);
            f16x4 s4 = { (_Float16)e0, (_Float16)e1, (_Float16)e2, (_Float16)e3 };
            *(f16x4*)&Xb[row * Ss + col] = s4;
        }
    }

    // ---- P -> PV A-fragments via cross-g shfl exchange ----
    // af[kkt][e] = P[s][32kkt + 8g + e]; source lane 16*(2(g&1)+(e>>2)) + l15,
    // tile tj = 2kkt + (g>>1).
    f16x8 af[4];
    const int kmax = w >> 1;
    {
        int a2 = (g & 1) * 2;
        int sA = a2 * 16 + l15;
        int sB = sA + 16;
        bool hi2 = (g >> 1) != 0;
#pragma unroll
        for (int kkt = 0; kkt < 4; kkt++) {
            if (kkt <= kmax) {
                unsigned xA0 = __shfl((int)plo[2*kkt],   sA);
                unsigned xA1 = __shfl((int)phi[2*kkt],   sA);
                unsigned xB0 = __shfl((int)plo[2*kkt],   sB);
                unsigned xB1 = __shfl((int)phi[2*kkt],   sB);
                unsigned yA0 = __shfl((int)plo[2*kkt+1], sA);
                unsigned yA1 = __shfl((int)phi[2*kkt+1], sA);
                unsigned yB0 = __shfl((int)plo[2*kkt+1], sB);
                unsigned yB1 = __shfl((int)phi[2*kkt+1], sB);
                U8 t;
                t.u[0] = hi2 ? yA0 : xA0;
                t.u[1] = hi2 ? yA1 : xA1;
                t.u[2] = hi2 ? yB0 : xB0;
                t.u[3] = hi2 ? yB1 : xB1;
                af[kkt] = t.v;
            }
        }
    }
    __syncthreads();   // barrier D: V^T staged

    // ---- per-lane output-row constants (s = S0+4g+r) ----
    float rnv[4], siwr[4];
#pragma unroll
    for (int r = 0; r < 4; r++) {
        int sr = S0 + 4 * g + r;
        rnv[r] = 1.0f / smn[sr];
        siwr[r] = siw[sr];
    }

    // ---- PV + inter + write, in two vj-halves (register economy) ----
#pragma unroll
    for (int half = 0; half < 2; half++) {
        f32x4 h4[4];
#pragma unroll
        for (int j = 0; j < 4; j++) h4[j] = (f32x4){0.f, 0.f, 0.f, 0.f};

#pragma unroll
        for (int kkt = 0; kkt < 4; kkt++) {
            if (kkt <= kmax) {
#pragma unroll
                for (int j = 0; j < 4; j++) {
                    int vr = (half * 4 + j) * 16 + l15;
                    f16x8 bv = *(const f16x8*)&Xb[vr * Ss + ((kkt * 32 + g * 8) ^ swt)];
                    h4[j] = __builtin_amdgcn_mfma_f32_16x16x32_f16(af[kkt], bv, h4[j], 0, 0, 0);
                }
            }
        }
#pragma unroll
        for (int j = 0; j < 4; j++) {
            int vr = (half * 4 + j) * 16 + l15;
            f32x4 tmp = {0.f, 0.f, 0.f, 0.f};
            const _Float16* cpr = cprevT + (size_t)vr * Kk + g * 8;
#pragma unroll
            for (int kk = 0; kk < 4; kk++) {
                f16x8 bcf = *(const f16x8*)(cpr + kk * 32);
                tmp = __builtin_amdgcn_mfma_f32_16x16x32_f16(qf[kk], bcf, tmp, 0, 0, 0);
            }
#pragma unroll
            for (int r = 0; r < 4; r++) {
                int sr = S0 + 4 * g + r;
                float o = (h4[j][r] + tmp[r] * siwr[r]) * rnv[r];
                out[(rowbase + sr) * Vv + vr] = o;
            }
        }
    }
}

// ---------------------------------------------------------------------------
extern "C" void kernel_launch(void* const* d_in, const int* in_sizes, int n_in,
                              void* d_out, int out_size, void* d_ws, size_t ws_size,
                              hipStream_t stream) {
    (void)in_sizes; (void)n_in; (void)out_size; (void)ws_size;
    const float* q  = (const float*)d_in[0];
    const float* k  = (const float*)d_in[1];
    const float* v  = (const float*)d_in[2];
    const float* ig = (const float*)d_in[3];
    const float* fg = (const float*)d_in[4];
    const float* C0 = (const float*)d_in[5];
    const float* n0 = (const float*)d_in[6];
    const float* m0 = (const float*)d_in[7];
    float* out = (float*)d_out;
    float* ws  = (float*)d_ws;

    k_kvg<<<BH * Cc, 512, 0, stream>>>(ig, fg, k, v, ws);
    k_scan_coef<<<1, 512, 0, stream>>>(m0, ws);
    k_scan_apply<<<(BH * Kk * Vv / 2 + BH * Kk) / 128, 128, 0, stream>>>(C0, n0, ws);
    k_out_mfma<<<BH * Cc, 512, 0, stream>>>(q, k, v, ig, ws, out);
}

// Round 9
// 68.858 us; speedup vs baseline: 1.0474x; 1.0474x over previous
//
#include <hip/hip_runtime.h>
#include <hip/hip_fp16.h>
#include <math.h>

#define Bb 2
#define Hh 8
#define Tt 4096
#define Kk 128
#define Vv 128
#define Ss 128
#define Cc 32
#define BH (Bb*Hh)
#define SCALE 0.08838834764831845f  /* 1/sqrt(128) */

// ---- workspace layout ----
#define OFF_LFACC  0                               // BH*Tt
#define OFF_LFLAST (OFF_LFACC + BH*Tt)             // BH*Cc
#define OFF_MINTRA (OFF_LFLAST + BH*Cc)
#define OFF_MPREV  (OFF_MINTRA + BH*Cc)
#define OFF_E1     (OFF_MPREV + BH*Cc)
#define OFF_E2     (OFF_E1 + BH*Cc)
#define OFF_KSUM   (OFF_E2 + BH*Cc)                // BH*Cc*Kk (fp32, becomes n_prev)
#define OFF_KVH    (OFF_KSUM + BH*Cc*Kk)           // fp16 kv^T [blk][v][k] (-> c_prev^T)

typedef _Float16 f16x8 __attribute__((ext_vector_type(8)));
typedef _Float16 f16x4 __attribute__((ext_vector_type(4)));
typedef _Float16 f16x2 __attribute__((ext_vector_type(2)));
typedef float f32x4 __attribute__((ext_vector_type(4)));

union U2 { f16x2 h; unsigned u; };
union U8 { f16x8 v; unsigned u[4]; };

// ---------------------------------------------------------------------------
// Kernel 1: fused gates + MFMA kv^T (fp16) + ksum. 512 threads, 8 waves.
// (unchanged from round 8 — validated)
// ---------------------------------------------------------------------------
__global__ __launch_bounds__(512, 4) void k_kvg(const float* __restrict__ ig,
                                                const float* __restrict__ fg,
                                                const float* __restrict__ kg,
                                                const float* __restrict__ vg,
                                                float* __restrict__ ws) {
    __shared__ _Float16 Kt[Ss * Ss];   // (g*K)^T [kidx][t], swizzled
    __shared__ _Float16 Vt[Ss * Ss];   // V^T [vidx][t], swizzled
    __shared__ float sfg[Ss];
    __shared__ float scomb[4];

    int blk = blockIdx.x;
    int bh = blk >> 5;
    int c  = blk & 31;
    int tid = threadIdx.x;
    int lane = tid & 63;
    int w = tid >> 6;
    int l15 = lane & 15;
    int g = lane >> 4;

    const float* kb = kg + ((size_t)bh * Tt + (size_t)c * Ss) * Kk;
    const float* vb = vg + ((size_t)bh * Tt + (size_t)c * Ss) * Vv;

    // ---- hoisted rep-0 staging loads (latency hides under gates) ----
    int c0a = (tid & 31) * 4;
    int t0a = (tid >> 5) * 4;
    const float* ksrcA = kb + (size_t)t0a * Kk + c0a;
    const float* vsrcA = vb + (size_t)t0a * Vv + c0a;
    float4 kA0 = *(const float4*)(ksrcA);
    float4 kA1 = *(const float4*)(ksrcA + Kk);
    float4 kA2 = *(const float4*)(ksrcA + 2 * Kk);
    float4 kA3 = *(const float4*)(ksrcA + 3 * Kk);
    float4 vA0 = *(const float4*)(vsrcA);
    float4 vA1 = *(const float4*)(vsrcA + Vv);
    float4 vA2 = *(const float4*)(vsrcA + 2 * Vv);
    float4 vA3 = *(const float4*)(vsrcA + 3 * Vv);

    // ---- gates (threads 0..127, shfl-based scan) ----
    bool p0 = tid < Ss;
    int lane64 = tid & 63;
    int wv = (tid >> 6) & 1;
    int gidx = bh * Tt + c * Ss + tid;
    float lfacc = 0.f, fwd = 0.f;
    if (p0) {
        float x  = fg[gidx];
        lfacc = fminf(x, 0.f) - log1pf(__expf(-fabsf(x)));
        for (int off = 1; off < 64; off <<= 1) {
            float o = __shfl_up(lfacc, off);
            if (lane64 >= off) lfacc += o;
        }
        if (lane64 == 63) scomb[wv] = lfacc;
    }
    __syncthreads();
    if (p0) {
        float tot0 = scomb[0];
        if (wv == 1) lfacc += tot0;
        float lflast = tot0 + scomb[1];
        fwd = ig[gidx] + lflast - lfacc;
        float mx = fwd;
        for (int off = 32; off; off >>= 1) mx = fmaxf(mx, __shfl_xor(mx, off));
        if (lane64 == 0) scomb[2 + wv] = mx;
    }
    __syncthreads();
    if (p0) {
        float mi = fmaxf(scomb[2], scomb[3]);
        sfg[tid] = __expf(fwd - mi);
        ws[OFF_LFACC + gidx] = lfacc;
        if (tid == 0) {
            ws[OFF_LFLAST + blk] = scomb[0] + scomb[1];
            ws[OFF_MINTRA + blk] = mi;
        }
    }
    __syncthreads();

    // ---- stage rep0 (from hoisted regs) ----
    {
        float g0 = sfg[t0a], g1 = sfg[t0a + 1], g2 = sfg[t0a + 2], g3 = sfg[t0a + 3];
#pragma unroll
        for (int jc = 0; jc < 4; jc++) {
            float ke0 = (jc == 0 ? kA0.x : jc == 1 ? kA0.y : jc == 2 ? kA0.z : kA0.w);
            float ke1 = (jc == 0 ? kA1.x : jc == 1 ? kA1.y : jc == 2 ? kA1.z : kA1.w);
            float ke2 = (jc == 0 ? kA2.x : jc == 1 ? kA2.y : jc == 2 ? kA2.z : kA2.w);
            float ke3 = (jc == 0 ? kA3.x : jc == 1 ? kA3.y : jc == 2 ? kA3.z : kA3.w);
            float ve0 = (jc == 0 ? vA0.x : jc == 1 ? vA0.y : jc == 2 ? vA0.z : vA0.w);
            float ve1 = (jc == 0 ? vA1.x : jc == 1 ? vA1.y : jc == 2 ? vA1.z : vA1.w);
            float ve2 = (jc == 0 ? vA2.x : jc == 1 ? vA2.y : jc == 2 ? vA2.z : vA2.w);
            float ve3 = (jc == 0 ? vA3.x : jc == 1 ? vA3.y : jc == 2 ? vA3.z : vA3.w);
            int row = c0a + jc;
            int col = t0a ^ ((row & 15) << 3);
            f16x4 kc = { (_Float16)(ke0 * g0), (_Float16)(ke1 * g1),
                         (_Float16)(ke2 * g2), (_Float16)(ke3 * g3) };
            f16x4 vc = { (_Float16)ve0, (_Float16)ve1, (_Float16)ve2, (_Float16)ve3 };
            *(f16x4*)&Kt[row * Ss + col] = kc;
            *(f16x4*)&Vt[row * Ss + col] = vc;
        }
    }
    // ---- stage rep1 (load now) ----
    {
        int tau = tid + 512;
        int c0 = (tau & 31) * 4;
        int t0 = (tau >> 5) * 4;
        const float* ksrc = kb + (size_t)t0 * Kk + c0;
        const float* vsrc = vb + (size_t)t0 * Vv + c0;
        float4 k0 = *(const float4*)(ksrc);
        float4 k1 = *(const float4*)(ksrc + Kk);
        float4 k2 = *(const float4*)(ksrc + 2 * Kk);
        float4 k3 = *(const float4*)(ksrc + 3 * Kk);
        float4 v0 = *(const float4*)(vsrc);
        float4 v1 = *(const float4*)(vsrc + Vv);
        float4 v2 = *(const float4*)(vsrc + 2 * Vv);
        float4 v3 = *(const float4*)(vsrc + 3 * Vv);
        float g0 = sfg[t0], g1 = sfg[t0 + 1], g2 = sfg[t0 + 2], g3 = sfg[t0 + 3];
#pragma unroll
        for (int jc = 0; jc < 4; jc++) {
            float ke0 = (jc == 0 ? k0.x : jc == 1 ? k0.y : jc == 2 ? k0.z : k0.w);
            float ke1 = (jc == 0 ? k1.x : jc == 1 ? k1.y : jc == 2 ? k1.z : k1.w);
            float ke2 = (jc == 0 ? k2.x : jc == 1 ? k2.y : jc == 2 ? k2.z : k2.w);
            float ke3 = (jc == 0 ? k3.x : jc == 1 ? k3.y : jc == 2 ? k3.z : k3.w);
            float ve0 = (jc == 0 ? v0.x : jc == 1 ? v0.y : jc == 2 ? v0.z : v0.w);
            float ve1 = (jc == 0 ? v1.x : jc == 1 ? v1.y : jc == 2 ? v1.z : v1.w);
            float ve2 = (jc == 0 ? v2.x : jc == 1 ? v2.y : jc == 2 ? v2.z : v2.w);
            float ve3 = (jc == 0 ? v3.x : jc == 1 ? v3.y : jc == 2 ? v3.z : v3.w);
            int row = c0 + jc;
            int col = t0 ^ ((row & 15) << 3);
            f16x4 kc = { (_Float16)(ke0 * g0), (_Float16)(ke1 * g1),
                         (_Float16)(ke2 * g2), (_Float16)(ke3 * g3) };
            f16x4 vc = { (_Float16)ve0, (_Float16)ve1, (_Float16)ve2, (_Float16)ve3 };
            *(f16x4*)&Kt[row * Ss + col] = kc;
            *(f16x4*)&Vt[row * Ss + col] = vc;
        }
    }
    __syncthreads();

    // ---- ksum: per-row reduction of Kt (threads 0..127) ----
    if (tid < Ss) {
        int sw = (tid & 15) << 3;
        float s = 0.f;
#pragma unroll
        for (int i = 0; i < 16; i++) {
            f16x8 ld = *(const f16x8*)&Kt[tid * Ss + ((8 * i) ^ sw)];
#pragma unroll
            for (int e = 0; e < 8; e++) s += (float)ld[e];
        }
        ws[OFF_KSUM + (size_t)blk * Kk + tid] = s;
    }

    // ---- MFMA (swapped): wave w -> vidx band [16w, 16w+16) ----
    const int band = w * 16;
    const int swt = l15 << 3;
    f16x8 af[4];
#pragma unroll
    for (int kk = 0; kk < 4; kk++)
        af[kk] = *(const f16x8*)&Vt[(band + l15) * Ss + ((kk * 32 + g * 8) ^ swt)];

    f32x4 acc[8];
#pragma unroll
    for (int kj = 0; kj < 8; kj++) acc[kj] = (f32x4){0.f, 0.f, 0.f, 0.f};

#pragma unroll
    for (int kj = 0; kj < 8; kj++) {
        int kr = kj * 16 + l15;
#pragma unroll
        for (int kk = 0; kk < 4; kk++) {
            f16x8 bv = *(const f16x8*)&Kt[kr * Ss + ((kk * 32 + g * 8) ^ swt)];
            acc[kj] = __builtin_amdgcn_mfma_f32_16x16x32_f16(af[kk], bv, acc[kj], 0, 0, 0);
        }
    }

    _Float16* dst = (_Float16*)(ws + OFF_KVH) + (size_t)blk * Kk * Vv;
#pragma unroll
    for (int kj = 0; kj < 8; kj++)
#pragma unroll
        for (int r = 0; r < 4; r++)
            dst[(size_t)(band + 4 * g + r) * Kk + kj * 16 + l15] = (_Float16)acc[kj][r];
}

// ---------------------------------------------------------------------------
// Kernel 2a: scan coefficients — fully parallel (m never updates).
// ---------------------------------------------------------------------------
__global__ __launch_bounds__(512) void k_scan_coef(const float* __restrict__ m0,
                                                   float* __restrict__ ws) {
    int t = threadIdx.x;             // t == blk == bh*Cc + c
    int bh = t >> 5;
    const float m = m0[bh];
    float lfl = ws[OFF_LFLAST + t];
    float mi  = ws[OFF_MINTRA + t];
    float mn  = fmaxf(lfl + m, mi);
    ws[OFF_MPREV + t] = m;
    ws[OFF_E1 + t] = __expf(lfl + m - mn);
    ws[OFF_E2 + t] = __expf(mi - mn);
}

// ---------------------------------------------------------------------------
// Kernel 2b: scan application with depth-2 prefetch (unchanged from round 8)
// ---------------------------------------------------------------------------
__global__ __launch_bounds__(128) void k_scan_apply(const float* __restrict__ C0,
                                                    const float* __restrict__ n0,
                                                    float* __restrict__ ws) {
    const int NC2 = BH * Kk * Vv / 2;     // 131072 f16x2 elements
    int gid = blockIdx.x * 128 + threadIdx.x;
    if (gid < NC2) {
        int bh = gid >> 13;
        int i  = gid & 8191;
        int v  = i >> 6;
        int k2 = (i & 63) << 1;
        float st0 = C0[(size_t)bh * Kk * Vv + (size_t)k2 * Vv + v];
        float st1 = C0[(size_t)bh * Kk * Vv + (size_t)(k2 + 1) * Vv + v];
        f16x2* base = (f16x2*)((_Float16*)(ws + OFF_KVH) +
                               (size_t)bh * Cc * Kk * Vv + (size_t)v * Kk + k2);
        const float* e1p = ws + OFF_E1 + bh * Cc;
        const float* e2p = ws + OFF_E2 + bh * Cc;
        const size_t stride = Kk * Vv / 2;
        f16x2 cur = base[0];
        f16x2 nxt = base[stride];
#pragma unroll
        for (int c = 0; c < Cc; c++) {
            f16x2 n2 = (c + 2 < Cc) ? base[(size_t)(c + 2) * stride]
                                    : (f16x2){(_Float16)0.f, (_Float16)0.f};
            f16x2 o = { (_Float16)st0, (_Float16)st1 };
            base[(size_t)c * stride] = o;          // c_prev^T for chunk c
            float e1 = e1p[c], e2 = e2p[c];
            st0 = st0 * e1 + (float)cur[0] * e2;
            st1 = st1 * e1 + (float)cur[1] * e2;
            cur = nxt; nxt = n2;
        }
    } else if (gid < NC2 + BH * Kk) {
        int g2 = gid - NC2;
        int bh = g2 / Kk;
        float st = n0[g2];
        float* base = ws + OFF_KSUM + (size_t)bh * Cc * Kk + (g2 % Kk);
        const float* e1p = ws + OFF_E1 + bh * Cc;
        const float* e2p = ws + OFF_E2 + bh * Cc;
        float cur = base[0];
        float nxt = base[Kk];
#pragma unroll
        for (int c = 0; c < Cc; c++) {
            float n2 = (c + 2 < Cc) ? base[(size_t)(c + 2) * Kk] : 0.f;
            float kvv = cur;
            base[(size_t)c * Kk] = st;             // n_prev for chunk c
            st = st * e1p[c] + kvv * e2p[c];
            cur = nxt; nxt = n2;
        }
    }
}

// ---------------------------------------------------------------------------
// Kernel 3 (v4): swapped-QK^T in-register P + SWAPPED PV/inter orientation.
// A = V^T / c_prev^T rows, B = P / q -> D[row=v][col=s] -> float4 stores.
// Conflict-free staging: K via b128 writes; V^T via interleaved rows
// (lane, lane+64) + scalar coalesced loads + b128 writes. Full &15 swizzle.
// launch_bounds(512,4): VGPR cap 128 — no spills (round-8 lesson).
// ---------------------------------------------------------------------------
__global__ __launch_bounds__(512, 4) void k_out_mfma(const float* __restrict__ qg,
                                                     const float* __restrict__ kg,
                                                     const float* __restrict__ vg,
                                                     const float* __restrict__ ig,
                                                     float* __restrict__ ws,
                                                     float* __restrict__ out) {
    __shared__ _Float16 Xb[Ss * Kk];    // K [t][k] then V^T [v][t], swizzled
    __shared__ float sbt[Ss], sas[Ss], siw[Ss], smn[Ss], slfa[Ss], snp[Ss];
    __shared__ float scomb[2];

    int blk = blockIdx.x;
    int bh = blk >> 5;
    int c  = blk & 31;
    int tid = threadIdx.x;
    int lane = tid & 63;
    int w = tid >> 6;                   // wave id 0..7; owns s in [16w,16w+16)
    int l15 = lane & 15;
    int g = lane >> 4;                  // 0..3
    const int S0 = w * 16;
    const int swt = l15 << 3;           // full &15 read swizzle

    const size_t rowbase = (size_t)bh * Tt + (size_t)c * Ss;
    const float* qp = qg + rowbase * Kk;
    const float* kp = kg + rowbase * Kk;
    const float* vp = vg + rowbase * Vv;
    const float* nprev = ws + OFF_KSUM + (size_t)blk * Kk;
    const _Float16* cprevT = (const _Float16*)(ws + OFF_KVH) + (size_t)blk * Kk * Vv;
    const float m_prev = ws[OFF_MPREV + blk];

    // ---- stage K [t][k], fp16, b128 writes (conflict-free) ----
    {
        int tK  = tid >> 2;
        int khK = (tid & 3) * 32;
        const float* src = kp + (size_t)tK * Kk + khK;
        int sw = (tK & 15) << 3;
#pragma unroll
        for (int i = 0; i < 4; i++) {
            float4 a = *(const float4*)&src[8 * i];
            float4 b = *(const float4*)&src[8 * i + 4];
            f16x8 h;
            h[0]=(_Float16)a.x; h[1]=(_Float16)a.y; h[2]=(_Float16)a.z; h[3]=(_Float16)a.w;
            h[4]=(_Float16)b.x; h[5]=(_Float16)b.y; h[6]=(_Float16)b.z; h[7]=(_Float16)b.w;
            int col = (khK + 8 * i) ^ sw;
            *(f16x8*)&Xb[tK * Kk + col] = h;
        }
    }

    // ---- Q fragments (B-layout): qf[kk][e] = q[S0+l15][kk*32+g*8+e] ----
    f16x8 qf[4];
#pragma unroll
    for (int kk = 0; kk < 4; kk++) {
        const float* p = qp + (size_t)(S0 + l15) * Kk + kk * 32 + g * 8;
        float4 a = *(const float4*)p;
        float4 b = *(const float4*)(p + 4);
        f16x8 r;
        r[0]=(_Float16)a.x; r[1]=(_Float16)a.y; r[2]=(_Float16)a.z; r[3]=(_Float16)a.w;
        r[4]=(_Float16)b.x; r[5]=(_Float16)b.y; r[6]=(_Float16)b.z; r[7]=(_Float16)b.w;
        qf[kk] = r;
    }

    // ---- phase 0 part 1: bt + prefix max (threads 0..127) ----
    bool p0 = tid < Ss;
    int lane64 = tid & 63;
    int wv = (tid >> 6) & 1;
    float pm = 0.f;
    if (p0) {
        float lfa = ws[OFF_LFACC + bh * Tt + c * Ss + tid];
        float bt = ig[bh * Tt + c * Ss + tid] - lfa;
        sbt[tid] = bt;
        slfa[tid] = lfa;
        snp[tid] = nprev[tid];
        pm = bt;
        for (int off = 1; off < 64; off <<= 1) {
            float o = __shfl_up(pm, off);
            if (lane64 >= off) pm = fmaxf(pm, o);
        }
        if (lane64 == 63) scomb[wv] = pm;
    }
    __syncthreads();   // barrier A: Xb(K), sbt/slfa/snp/scomb ready

    if (p0) {
        if (wv == 1) pm = fmaxf(pm, scomb[0]);
        float mx = fmaxf(pm, m_prev);
        sas[tid] = -mx;
        siw[tid] = SCALE * __expf(m_prev - mx);
    }
    // intern raw dot: q[s].n_prev, s = S0+l15
    float dotq = 0.f;
#pragma unroll
    for (int kk = 0; kk < 4; kk++)
#pragma unroll
        for (int e = 0; e < 8; e++)
            dotq += (float)qf[kk][e] * snp[kk * 32 + g * 8 + e];
    dotq += __shfl_xor(dotq, 16);
    dotq += __shfl_xor(dotq, 32);
    __syncthreads();   // barrier B: sas/siw ready

    const float as_s = sas[S0 + l15];
    const float iw_s = siw[S0 + l15];
    const float lfa_s = slfa[S0 + l15];

    // ---- swapped QK^T: lane gets P[s=S0+l15][t=16tj+4g+r] ----
    unsigned plo[8] = {0,0,0,0,0,0,0,0};
    unsigned phi[8] = {0,0,0,0,0,0,0,0};
    float rs = 0.f;
#pragma unroll
    for (int tj = 0; tj < 8; tj++) {
        if (tj <= w) {
            int trow = tj * 16 + l15;
            f16x8 bfr[4];
#pragma unroll
            for (int kk = 0; kk < 4; kk++)
                bfr[kk] = *(const f16x8*)&Xb[trow * Kk + ((kk * 32 + g * 8) ^ swt)];
            f32x4 acc = {0.f, 0.f, 0.f, 0.f};
#pragma unroll
            for (int kk = 0; kk < 4; kk++)
                acc = __builtin_amdgcn_mfma_f32_16x16x32_f16(bfr[kk], qf[kk], acc, 0, 0, 0);
            float vals[4];
#pragma unroll
            for (int r = 0; r < 4; r++) {
                int t = tj * 16 + 4 * g + r;
                float btv = sbt[t];
                float val = acc[r] * SCALE * __expf(as_s + btv);
                if (tj == w && (4 * g + r) > l15) val = 0.f;   // causal mask
                rs += val;
                vals[r] = val;
            }
            U2 lo, hi;
            lo.h = (f16x2){ (_Float16)vals[0], (_Float16)vals[1] };
            hi.h = (f16x2){ (_Float16)vals[2], (_Float16)vals[3] };
            plo[tj] = lo.u;
            phi[tj] = hi.u;
        }
    }
    // row sum across g-groups -> full sum for s = S0+l15
    rs += __shfl_xor(rs, 16);
    rs += __shfl_xor(rs, 32);
    {
        float engs = __expf(as_s - lfa_s);          // exp(-(lfa+mx))
        float mn = fmaxf(fabsf(rs + dotq * iw_s), engs);
        if (g == 0) smn[S0 + l15] = mn;
    }
    __syncthreads();   // barrier C: all QK^T reads of Xb done; smn written

    // ---- stage V^T [v][t]: interleaved rows (lane, lane+64), b128 writes ----
#pragma unroll
    for (int rep = 0; rep < 2; rep++) {
        int t0 = ((rep << 3) | w) * 8;              // 0..120 step 8
        float va[8], vb2[8];
#pragma unroll
        for (int i = 0; i < 8; i++) {
            va[i]  = vp[(size_t)(t0 + i) * Vv + lane];
            vb2[i] = vp[(size_t)(t0 + i) * Vv + lane + 64];
        }
        f16x8 ha, hb;
#pragma unroll
        for (int i = 0; i < 8; i++) { ha[i] = (_Float16)va[i]; hb[i] = (_Float16)vb2[i]; }
        int sw = (lane & 15) << 3;
        *(f16x8*)&Xb[lane * Ss + (t0 ^ sw)] = ha;
        *(f16x8*)&Xb[(lane + 64) * Ss + (t0 ^ sw)] = hb;
    }

    // ---- P -> B-operand fragments via cross-g shfl exchange ----
    // pb[kkt][e] = P[s=S0+l15][32kkt + 8g + e]
    f16x8 pb[4];
    const int kmax = w >> 1;
    {
        int a2 = (g & 1) * 2;
        int sA = a2 * 16 + l15;
        int sB = sA + 16;
        bool hi2 = (g >> 1) != 0;
#pragma unroll
        for (int kkt = 0; kkt < 4; kkt++) {
            if (kkt <= kmax) {
                unsigned xA0 = __shfl((int)plo[2*kkt],   sA);
                unsigned xA1 = __shfl((int)phi[2*kkt],   sA);
                unsigned xB0 = __shfl((int)plo[2*kkt],   sB);
                unsigned xB1 = __shfl((int)phi[2*kkt],   sB);
                unsigned yA0 = __shfl((int)plo[2*kkt+1], sA);
                unsigned yA1 = __shfl((int)phi[2*kkt+1], sA);
                unsigned yB0 = __shfl((int)plo[2*kkt+1], sB);
                unsigned yB1 = __shfl((int)phi[2*kkt+1], sB);
                U8 t;
                t.u[0] = hi2 ? yA0 : xA0;
                t.u[1] = hi2 ? yA1 : xA1;
                t.u[2] = hi2 ? yB0 : xB0;
                t.u[3] = hi2 ? yB1 : xB1;
                pb[kkt] = t.v;
            }
        }
    }
    __syncthreads();   // barrier D: V^T staged

    // ---- per-lane output constants (s = S0+l15) ----
    const float rnv_s = 1.0f / smn[S0 + l15];

    // ---- PV + inter + write (swapped: D[row=v][col=s]), two vj-halves ----
#pragma unroll
    for (int half = 0; half < 2; half++) {
        f32x4 h4[4];
#pragma unroll
        for (int j = 0; j < 4; j++) h4[j] = (f32x4){0.f, 0.f, 0.f, 0.f};

#pragma unroll
        for (int kkt = 0; kkt < 4; kkt++) {
            if (kkt <= kmax) {
#pragma unroll
                for (int j = 0; j < 4; j++) {
                    int vr = (half * 4 + j) * 16 + l15;
                    f16x8 av = *(const f16x8*)&Xb[vr * Ss + ((kkt * 32 + g * 8) ^ swt)];
                    h4[j] = __builtin_amdgcn_mfma_f32_16x16x32_f16(av, pb[kkt], h4[j], 0, 0, 0);
                }
            }
        }
#pragma unroll
        for (int j = 0; j < 4; j++) {
            int vr = (half * 4 + j) * 16 + l15;
            f32x4 tmp = {0.f, 0.f, 0.f, 0.f};
            const _Float16* cpr = cprevT + (size_t)vr * Kk + g * 8;
#pragma unroll
            for (int kk = 0; kk < 4; kk++) {
                f16x8 bcf = *(const f16x8*)(cpr + kk * 32);
                tmp = __builtin_amdgcn_mfma_f32_16x16x32_f16(bcf, qf[kk], tmp, 0, 0, 0);
            }
            // D[row=4g+r -> v=(half*4+j)*16+4g+r][col=l15 -> s=S0+l15]
            float4 o;
            o.x = (h4[j][0] + tmp[0] * iw_s) * rnv_s;
            o.y = (h4[j][1] + tmp[1] * iw_s) * rnv_s;
            o.z = (h4[j][2] + tmp[2] * iw_s) * rnv_s;
            o.w = (h4[j][3] + tmp[3] * iw_s) * rnv_s;
            *(float4*)&out[(rowbase + S0 + l15) * Vv + (half * 4 + j) * 16 + 4 * g] = o;
        }
    }
}

// ---------------------------------------------------------------------------
extern "C" void kernel_launch(void* const* d_in, const int* in_sizes, int n_in,
                              void* d_out, int out_size, void* d_ws, size_t ws_size,
                              hipStream_t stream) {
    (void)in_sizes; (void)n_in; (void)out_size; (void)ws_size;
    const float* q  = (const float*)d_in[0];
    const float* k  = (const float*)d_in[1];
    const float* v  = (const float*)d_in[2];
    const float* ig = (const float*)d_in[3];
    const float* fg = (const float*)d_in[4];
    const float* C0 = (const float*)d_in[5];
    const float* n0 = (const float*)d_in[6];
    const float* m0 = (const float*)d_in[7];
    float* out = (float*)d_out;
    float* ws  = (float*)d_ws;

    k_kvg<<<BH * Cc, 512, 0, stream>>>(ig, fg, k, v, ws);
    k_scan_coef<<<1, 512, 0, stream>>>(m0, ws);
    k_scan_apply<<<(BH * Kk * Vv / 2 + BH * Kk) / 128, 128, 0, stream>>>(C0, n0, ws);
    k_out_mfma<<<BH * Cc, 512, 0, stream>>>(q, k, v, ig, ws, out);
}

// Round 10
// 63.229 us; speedup vs baseline: 1.1406x; 1.0890x over previous
//
#include <hip/hip_runtime.h>
#include <hip/hip_fp16.h>
#include <math.h>

#define Bb 2
#define Hh 8
#define Tt 4096
#define Kk 128
#define Vv 128
#define Ss 128
#define Cc 32
#define BH (Bb*Hh)
#define SCALE 0.08838834764831845f  /* 1/sqrt(128) */

// ---- workspace layout ----
#define OFF_LFACC  0                               // BH*Tt
#define OFF_LFLAST (OFF_LFACC + BH*Tt)             // BH*Cc
#define OFF_MINTRA (OFF_LFLAST + BH*Cc)
#define OFF_KSUM   (OFF_MINTRA + BH*Cc)            // BH*Cc*Kk (fp32, becomes n_prev)
#define OFF_KVH    (OFF_KSUM + BH*Cc*Kk)           // fp16 kv^T [blk][v][k] (-> c_prev^T)

typedef _Float16 f16x8 __attribute__((ext_vector_type(8)));
typedef _Float16 f16x4 __attribute__((ext_vector_type(4)));
typedef _Float16 f16x2 __attribute__((ext_vector_type(2)));
typedef float f32x4 __attribute__((ext_vector_type(4)));

union U2 { f16x2 h; unsigned u; };
union U8 { f16x8 v; unsigned u[4]; };

// ---------------------------------------------------------------------------
// Kernel 1: fused gates + MFMA kv^T (fp16) + ksum. 512 threads, 8 waves.
// BOTH staging reps' k/v global loads hoisted above the gates phase.
// ---------------------------------------------------------------------------
__global__ __launch_bounds__(512, 4) void k_kvg(const float* __restrict__ ig,
                                                const float* __restrict__ fg,
                                                const float* __restrict__ kg,
                                                const float* __restrict__ vg,
                                                float* __restrict__ ws) {
    __shared__ _Float16 Kt[Ss * Ss];   // (g*K)^T [kidx][t], swizzled
    __shared__ _Float16 Vt[Ss * Ss];   // V^T [vidx][t], swizzled
    __shared__ float sfg[Ss];
    __shared__ float scomb[4];

    int blk = blockIdx.x;
    int bh = blk >> 5;
    int c  = blk & 31;
    int tid = threadIdx.x;
    int lane = tid & 63;
    int w = tid >> 6;
    int l15 = lane & 15;
    int g = lane >> 4;

    const float* kb = kg + ((size_t)bh * Tt + (size_t)c * Ss) * Kk;
    const float* vb = vg + ((size_t)bh * Tt + (size_t)c * Ss) * Vv;

    // ---- hoisted staging loads, BOTH reps (latency hides under gates) ----
    int c0a = (tid & 31) * 4;
    int t0a = (tid >> 5) * 4;
    const float* ksrcA = kb + (size_t)t0a * Kk + c0a;
    const float* vsrcA = vb + (size_t)t0a * Vv + c0a;
    float4 kA0 = *(const float4*)(ksrcA);
    float4 kA1 = *(const float4*)(ksrcA + Kk);
    float4 kA2 = *(const float4*)(ksrcA + 2 * Kk);
    float4 kA3 = *(const float4*)(ksrcA + 3 * Kk);
    float4 vA0 = *(const float4*)(vsrcA);
    float4 vA1 = *(const float4*)(vsrcA + Vv);
    float4 vA2 = *(const float4*)(vsrcA + 2 * Vv);
    float4 vA3 = *(const float4*)(vsrcA + 3 * Vv);
    int tau1 = tid + 512;
    int c0b = (tau1 & 31) * 4;
    int t0b = (tau1 >> 5) * 4;
    const float* ksrcB = kb + (size_t)t0b * Kk + c0b;
    const float* vsrcB = vb + (size_t)t0b * Vv + c0b;
    float4 kB0 = *(const float4*)(ksrcB);
    float4 kB1 = *(const float4*)(ksrcB + Kk);
    float4 kB2 = *(const float4*)(ksrcB + 2 * Kk);
    float4 kB3 = *(const float4*)(ksrcB + 3 * Kk);
    float4 vB0 = *(const float4*)(vsrcB);
    float4 vB1 = *(const float4*)(vsrcB + Vv);
    float4 vB2 = *(const float4*)(vsrcB + 2 * Vv);
    float4 vB3 = *(const float4*)(vsrcB + 3 * Vv);

    // ---- gates (threads 0..127, shfl-based scan) ----
    bool p0 = tid < Ss;
    int lane64 = tid & 63;
    int wv = (tid >> 6) & 1;
    int gidx = bh * Tt + c * Ss + tid;
    float lfacc = 0.f, fwd = 0.f;
    if (p0) {
        float x  = fg[gidx];
        lfacc = fminf(x, 0.f) - log1pf(__expf(-fabsf(x)));
        for (int off = 1; off < 64; off <<= 1) {
            float o = __shfl_up(lfacc, off);
            if (lane64 >= off) lfacc += o;
        }
        if (lane64 == 63) scomb[wv] = lfacc;
    }
    __syncthreads();
    if (p0) {
        float tot0 = scomb[0];
        if (wv == 1) lfacc += tot0;
        float lflast = tot0 + scomb[1];
        fwd = ig[gidx] + lflast - lfacc;
        float mx = fwd;
        for (int off = 32; off; off >>= 1) mx = fmaxf(mx, __shfl_xor(mx, off));
        if (lane64 == 0) scomb[2 + wv] = mx;
    }
    __syncthreads();
    if (p0) {
        float mi = fmaxf(scomb[2], scomb[3]);
        sfg[tid] = __expf(fwd - mi);
        ws[OFF_LFACC + gidx] = lfacc;
        if (tid == 0) {
            ws[OFF_LFLAST + blk] = scomb[0] + scomb[1];
            ws[OFF_MINTRA + blk] = mi;
        }
    }
    __syncthreads();

    // ---- stage rep0 (from hoisted regs) ----
    {
        float g0 = sfg[t0a], g1 = sfg[t0a + 1], g2 = sfg[t0a + 2], g3 = sfg[t0a + 3];
#pragma unroll
        for (int jc = 0; jc < 4; jc++) {
            float ke0 = (jc == 0 ? kA0.x : jc == 1 ? kA0.y : jc == 2 ? kA0.z : kA0.w);
            float ke1 = (jc == 0 ? kA1.x : jc == 1 ? kA1.y : jc == 2 ? kA1.z : kA1.w);
            float ke2 = (jc == 0 ? kA2.x : jc == 1 ? kA2.y : jc == 2 ? kA2.z : kA2.w);
            float ke3 = (jc == 0 ? kA3.x : jc == 1 ? kA3.y : jc == 2 ? kA3.z : kA3.w);
            float ve0 = (jc == 0 ? vA0.x : jc == 1 ? vA0.y : jc == 2 ? vA0.z : vA0.w);
            float ve1 = (jc == 0 ? vA1.x : jc == 1 ? vA1.y : jc == 2 ? vA1.z : vA1.w);
            float ve2 = (jc == 0 ? vA2.x : jc == 1 ? vA2.y : jc == 2 ? vA2.z : vA2.w);
            float ve3 = (jc == 0 ? vA3.x : jc == 1 ? vA3.y : jc == 2 ? vA3.z : vA3.w);
            int row = c0a + jc;
            int col = t0a ^ ((row & 15) << 3);
            f16x4 kc = { (_Float16)(ke0 * g0), (_Float16)(ke1 * g1),
                         (_Float16)(ke2 * g2), (_Float16)(ke3 * g3) };
            f16x4 vc = { (_Float16)ve0, (_Float16)ve1, (_Float16)ve2, (_Float16)ve3 };
            *(f16x4*)&Kt[row * Ss + col] = kc;
            *(f16x4*)&Vt[row * Ss + col] = vc;
        }
    }
    // ---- stage rep1 (from hoisted regs) ----
    {
        float g0 = sfg[t0b], g1 = sfg[t0b + 1], g2 = sfg[t0b + 2], g3 = sfg[t0b + 3];
#pragma unroll
        for (int jc = 0; jc < 4; jc++) {
            float ke0 = (jc == 0 ? kB0.x : jc == 1 ? kB0.y : jc == 2 ? kB0.z : kB0.w);
            float ke1 = (jc == 0 ? kB1.x : jc == 1 ? kB1.y : jc == 2 ? kB1.z : kB1.w);
            float ke2 = (jc == 0 ? kB2.x : jc == 1 ? kB2.y : jc == 2 ? kB2.z : kB2.w);
            float ke3 = (jc == 0 ? kB3.x : jc == 1 ? kB3.y : jc == 2 ? kB3.z : kB3.w);
            float ve0 = (jc == 0 ? vB0.x : jc == 1 ? vB0.y : jc == 2 ? vB0.z : vB0.w);
            float ve1 = (jc == 0 ? vB1.x : jc == 1 ? vB1.y : jc == 2 ? vB1.z : vB1.w);
            float ve2 = (jc == 0 ? vB2.x : jc == 1 ? vB2.y : jc == 2 ? vB2.z : vB2.w);
            float ve3 = (jc == 0 ? vB3.x : jc == 1 ? vB3.y : jc == 2 ? vB3.z : vB3.w);
            int row = c0b + jc;
            int col = t0b ^ ((row & 15) << 3);
            f16x4 kc = { (_Float16)(ke0 * g0), (_Float16)(ke1 * g1),
                         (_Float16)(ke2 * g2), (_Float16)(ke3 * g3) };
            f16x4 vc = { (_Float16)ve0, (_Float16)ve1, (_Float16)ve2, (_Float16)ve3 };
            *(f16x4*)&Kt[row * Ss + col] = kc;
            *(f16x4*)&Vt[row * Ss + col] = vc;
        }
    }
    __syncthreads();

    // ---- ksum: per-row reduction of Kt (threads 0..127) ----
    if (tid < Ss) {
        int sw = (tid & 15) << 3;
        float s = 0.f;
#pragma unroll
        for (int i = 0; i < 16; i++) {
            f16x8 ld = *(const f16x8*)&Kt[tid * Ss + ((8 * i) ^ sw)];
#pragma unroll
            for (int e = 0; e < 8; e++) s += (float)ld[e];
        }
        ws[OFF_KSUM + (size_t)blk * Kk + tid] = s;
    }

    // ---- MFMA (swapped): wave w -> vidx band [16w, 16w+16) ----
    const int band = w * 16;
    const int swt = l15 << 3;
    f16x8 af[4];
#pragma unroll
    for (int kk = 0; kk < 4; kk++)
        af[kk] = *(const f16x8*)&Vt[(band + l15) * Ss + ((kk * 32 + g * 8) ^ swt)];

    f32x4 acc[8];
#pragma unroll
    for (int kj = 0; kj < 8; kj++) acc[kj] = (f32x4){0.f, 0.f, 0.f, 0.f};

#pragma unroll
    for (int kj = 0; kj < 8; kj++) {
        int kr = kj * 16 + l15;
#pragma unroll
        for (int kk = 0; kk < 4; kk++) {
            f16x8 bv = *(const f16x8*)&Kt[kr * Ss + ((kk * 32 + g * 8) ^ swt)];
            acc[kj] = __builtin_amdgcn_mfma_f32_16x16x32_f16(af[kk], bv, acc[kj], 0, 0, 0);
        }
    }

    _Float16* dst = (_Float16*)(ws + OFF_KVH) + (size_t)blk * Kk * Vv;
#pragma unroll
    for (int kj = 0; kj < 8; kj++)
#pragma unroll
        for (int r = 0; r < 4; r++)
            dst[(size_t)(band + 4 * g + r) * Kk + kj * 16 + l15] = (_Float16)acc[kj][r];
}

// ---------------------------------------------------------------------------
// Kernel 2: scan application. Coefficients (e1/e2) computed BLOCK-LOCALLY
// (each 128-thread block spans exactly one bh; reference quirk m==m0 makes
// every chunk's coefficients independent). k_scan_coef launch eliminated.
// ---------------------------------------------------------------------------
__global__ __launch_bounds__(128) void k_scan_apply(const float* __restrict__ C0,
                                                    const float* __restrict__ n0,
                                                    const float* __restrict__ m0,
                                                    float* __restrict__ ws) {
    __shared__ float se1[Cc], se2[Cc];
    const int NC2 = BH * Kk * Vv / 2;     // 131072 f16x2 elements
    int gid = blockIdx.x * 128 + threadIdx.x;
    bool main_r = gid < NC2;
    int bh = main_r ? (gid >> 13) : ((gid - NC2) >> 7);

    if (threadIdx.x < Cc) {
        int cc = threadIdx.x;
        float m   = m0[bh];
        float lfl = ws[OFF_LFLAST + bh * Cc + cc];
        float mi  = ws[OFF_MINTRA + bh * Cc + cc];
        float mn  = fmaxf(lfl + m, mi);
        se1[cc] = __expf(lfl + m - mn);
        se2[cc] = __expf(mi - mn);
    }
    __syncthreads();

    if (main_r) {
        int i  = gid & 8191;
        int v  = i >> 6;
        int k2 = (i & 63) << 1;
        float st0 = C0[(size_t)bh * Kk * Vv + (size_t)k2 * Vv + v];
        float st1 = C0[(size_t)bh * Kk * Vv + (size_t)(k2 + 1) * Vv + v];
        f16x2* base = (f16x2*)((_Float16*)(ws + OFF_KVH) +
                               (size_t)bh * Cc * Kk * Vv + (size_t)v * Kk + k2);
        const size_t stride = Kk * Vv / 2;
        f16x2 cur = base[0];
        f16x2 nxt = base[stride];
#pragma unroll
        for (int c = 0; c < Cc; c++) {
            f16x2 n2 = (c + 2 < Cc) ? base[(size_t)(c + 2) * stride]
                                    : (f16x2){(_Float16)0.f, (_Float16)0.f};
            f16x2 o = { (_Float16)st0, (_Float16)st1 };
            base[(size_t)c * stride] = o;          // c_prev^T for chunk c
            float e1 = se1[c], e2 = se2[c];
            st0 = st0 * e1 + (float)cur[0] * e2;
            st1 = st1 * e1 + (float)cur[1] * e2;
            cur = nxt; nxt = n2;
        }
    } else if (gid < NC2 + BH * Kk) {
        int g2 = gid - NC2;
        float st = n0[g2];
        float* base = ws + OFF_KSUM + (size_t)bh * Cc * Kk + (g2 & (Kk - 1));
        float cur = base[0];
        float nxt = base[Kk];
#pragma unroll
        for (int c = 0; c < Cc; c++) {
            float n2 = (c + 2 < Cc) ? base[(size_t)(c + 2) * Kk] : 0.f;
            float kvv = cur;
            base[(size_t)c * Kk] = st;             // n_prev for chunk c
            st = st * se1[c] + kvv * se2[c];
            cur = nxt; nxt = n2;
        }
    }
}

// ---------------------------------------------------------------------------
// Kernel 3 (v5): v4 + hoisted V staging loads (issue after barrier A,
// convert to fp16 before QK^T, LDS-write after barrier C). m_prev = m0[bh].
// ---------------------------------------------------------------------------
__global__ __launch_bounds__(512, 4) void k_out_mfma(const float* __restrict__ qg,
                                                     const float* __restrict__ kg,
                                                     const float* __restrict__ vg,
                                                     const float* __restrict__ ig,
                                                     const float* __restrict__ m0,
                                                     float* __restrict__ ws,
                                                     float* __restrict__ out) {
    __shared__ _Float16 Xb[Ss * Kk];    // K [t][k] then V^T [v][t], swizzled
    __shared__ float sbt[Ss], sas[Ss], siw[Ss], smn[Ss], slfa[Ss], snp[Ss];
    __shared__ float scomb[2];

    int blk = blockIdx.x;
    int bh = blk >> 5;
    int c  = blk & 31;
    int tid = threadIdx.x;
    int lane = tid & 63;
    int w = tid >> 6;                   // wave id 0..7; owns s in [16w,16w+16)
    int l15 = lane & 15;
    int g = lane >> 4;                  // 0..3
    const int S0 = w * 16;
    const int swt = l15 << 3;           // full &15 read swizzle

    const size_t rowbase = (size_t)bh * Tt + (size_t)c * Ss;
    const float* qp = qg + rowbase * Kk;
    const float* kp = kg + rowbase * Kk;
    const float* vp = vg + rowbase * Vv;
    const float* nprev = ws + OFF_KSUM + (size_t)blk * Kk;
    const _Float16* cprevT = (const _Float16*)(ws + OFF_KVH) + (size_t)blk * Kk * Vv;
    const float m_prev = m0[bh];        // reference quirk: m never rebinds

    // ---- stage K [t][k], fp16, b128 writes (conflict-free) ----
    {
        int tK  = tid >> 2;
        int khK = (tid & 3) * 32;
        const float* src = kp + (size_t)tK * Kk + khK;
        int sw = (tK & 15) << 3;
#pragma unroll
        for (int i = 0; i < 4; i++) {
            float4 a = *(const float4*)&src[8 * i];
            float4 b = *(const float4*)&src[8 * i + 4];
            f16x8 h;
            h[0]=(_Float16)a.x; h[1]=(_Float16)a.y; h[2]=(_Float16)a.z; h[3]=(_Float16)a.w;
            h[4]=(_Float16)b.x; h[5]=(_Float16)b.y; h[6]=(_Float16)b.z; h[7]=(_Float16)b.w;
            int col = (khK + 8 * i) ^ sw;
            *(f16x8*)&Xb[tK * Kk + col] = h;
        }
    }

    // ---- Q fragments (B-layout): qf[kk][e] = q[S0+l15][kk*32+g*8+e] ----
    f16x8 qf[4];
#pragma unroll
    for (int kk = 0; kk < 4; kk++) {
        const float* p = qp + (size_t)(S0 + l15) * Kk + kk * 32 + g * 8;
        float4 a = *(const float4*)p;
        float4 b = *(const float4*)(p + 4);
        f16x8 r;
        r[0]=(_Float16)a.x; r[1]=(_Float16)a.y; r[2]=(_Float16)a.z; r[3]=(_Float16)a.w;
        r[4]=(_Float16)b.x; r[5]=(_Float16)b.y; r[6]=(_Float16)b.z; r[7]=(_Float16)b.w;
        qf[kk] = r;
    }

    // ---- phase 0 part 1: bt + prefix max (threads 0..127) ----
    bool p0 = tid < Ss;
    int lane64 = tid & 63;
    int wv = (tid >> 6) & 1;
    float pm = 0.f;
    if (p0) {
        float lfa = ws[OFF_LFACC + bh * Tt + c * Ss + tid];
        float bt = ig[bh * Tt + c * Ss + tid] - lfa;
        sbt[tid] = bt;
        slfa[tid] = lfa;
        snp[tid] = nprev[tid];
        pm = bt;
        for (int off = 1; off < 64; off <<= 1) {
            float o = __shfl_up(pm, off);
            if (lane64 >= off) pm = fmaxf(pm, o);
        }
        if (lane64 == 63) scomb[wv] = pm;
    }
    __syncthreads();   // barrier A: Xb(K), sbt/slfa/snp/scomb ready

    // ---- hoisted V staging loads (T14): rows t0A/t0B = (rep*8+w)*8 ----
    const int t0A = w * 8;
    const int t0B = (8 + w) * 8;
    float vra[8], vrb[8], vrc[8], vrd[8];
#pragma unroll
    for (int i = 0; i < 8; i++) {
        vra[i] = vp[(size_t)(t0A + i) * Vv + lane];
        vrb[i] = vp[(size_t)(t0A + i) * Vv + lane + 64];
        vrc[i] = vp[(size_t)(t0B + i) * Vv + lane];
        vrd[i] = vp[(size_t)(t0B + i) * Vv + lane + 64];
    }

    if (p0) {
        if (wv == 1) pm = fmaxf(pm, scomb[0]);
        float mx = fmaxf(pm, m_prev);
        sas[tid] = -mx;
        siw[tid] = SCALE * __expf(m_prev - mx);
    }
    // intern raw dot: q[s].n_prev, s = S0+l15
    float dotq = 0.f;
#pragma unroll
    for (int kk = 0; kk < 4; kk++)
#pragma unroll
        for (int e = 0; e < 8; e++)
            dotq += (float)qf[kk][e] * snp[kk * 32 + g * 8 + e];
    dotq += __shfl_xor(dotq, 16);
    dotq += __shfl_xor(dotq, 32);

    // convert hoisted V to fp16 (frees 32 fp32 regs -> 16 f16 regs)
    f16x8 hva, hvb, hvc, hvd;
#pragma unroll
    for (int i = 0; i < 8; i++) {
        hva[i] = (_Float16)vra[i];  hvb[i] = (_Float16)vrb[i];
        hvc[i] = (_Float16)vrc[i];  hvd[i] = (_Float16)vrd[i];
    }
    __syncthreads();   // barrier B: sas/siw ready

    const float as_s = sas[S0 + l15];
    const float iw_s = siw[S0 + l15];
    const float lfa_s = slfa[S0 + l15];

    // ---- swapped QK^T: lane gets P[s=S0+l15][t=16tj+4g+r] ----
    unsigned plo[8] = {0,0,0,0,0,0,0,0};
    unsigned phi[8] = {0,0,0,0,0,0,0,0};
    float rs = 0.f;
#pragma unroll
    for (int tj = 0; tj < 8; tj++) {
        if (tj <= w) {
            int trow = tj * 16 + l15;
            f16x8 bfr[4];
#pragma unroll
            for (int kk = 0; kk < 4; kk++)
                bfr[kk] = *(const f16x8*)&Xb[trow * Kk + ((kk * 32 + g * 8) ^ swt)];
            f32x4 acc = {0.f, 0.f, 0.f, 0.f};
#pragma unroll
            for (int kk = 0; kk < 4; kk++)
                acc = __builtin_amdgcn_mfma_f32_16x16x32_f16(bfr[kk], qf[kk], acc, 0, 0, 0);
            float vals[4];
#pragma unroll
            for (int r = 0; r < 4; r++) {
                int t = tj * 16 + 4 * g + r;
                float btv = sbt[t];
                float val = acc[r] * SCALE * __expf(as_s + btv);
                if (tj == w && (4 * g + r) > l15) val = 0.f;   // causal mask
                rs += val;
                vals[r] = val;
            }
            U2 lo, hi;
            lo.h = (f16x2){ (_Float16)vals[0], (_Float16)vals[1] };
            hi.h = (f16x2){ (_Float16)vals[2], (_Float16)vals[3] };
            plo[tj] = lo.u;
            phi[tj] = hi.u;
        }
    }
    // row sum across g-groups -> full sum for s = S0+l15
    rs += __shfl_xor(rs, 16);
    rs += __shfl_xor(rs, 32);
    {
        float engs = __expf(as_s - lfa_s);          // exp(-(lfa+mx))
        float mn = fmaxf(fabsf(rs + dotq * iw_s), engs);
        if (g == 0) smn[S0 + l15] = mn;
    }
    __syncthreads();   // barrier C: all QK^T reads of Xb done; smn written

    // ---- write hoisted V^T into Xb (b128, conflict-free) ----
    {
        int sw = (lane & 15) << 3;
        *(f16x8*)&Xb[lane * Ss + (t0A ^ sw)] = hva;
        *(f16x8*)&Xb[(lane + 64) * Ss + (t0A ^ sw)] = hvb;
        *(f16x8*)&Xb[lane * Ss + (t0B ^ sw)] = hvc;
        *(f16x8*)&Xb[(lane + 64) * Ss + (t0B ^ sw)] = hvd;
    }

    // ---- P -> B-operand fragments via cross-g shfl exchange ----
    f16x8 pb[4];
    const int kmax = w >> 1;
    {
        int a2 = (g & 1) * 2;
        int sA = a2 * 16 + l15;
        int sB = sA + 16;
        bool hi2 = (g >> 1) != 0;
#pragma unroll
        for (int kkt = 0; kkt < 4; kkt++) {
            if (kkt <= kmax) {
                unsigned xA0 = __shfl((int)plo[2*kkt],   sA);
                unsigned xA1 = __shfl((int)phi[2*kkt],   sA);
                unsigned xB0 = __shfl((int)plo[2*kkt],   sB);
                unsigned xB1 = __shfl((int)phi[2*kkt],   sB);
                unsigned yA0 = __shfl((int)plo[2*kkt+1], sA);
                unsigned yA1 = __shfl((int)phi[2*kkt+1], sA);
                unsigned yB0 = __shfl((int)plo[2*kkt+1], sB);
                unsigned yB1 = __shfl((int)phi[2*kkt+1], sB);
                U8 t;
                t.u[0] = hi2 ? yA0 : xA0;
                t.u[1] = hi2 ? yA1 : xA1;
                t.u[2] = hi2 ? yB0 : xB0;
                t.u[3] = hi2 ? yB1 : xB1;
                pb[kkt] = t.v;
            }
        }
    }
    __syncthreads();   // barrier D: V^T staged

    // ---- per-lane output constants (s = S0+l15) ----
    const float rnv_s = 1.0f / smn[S0 + l15];

    // ---- PV + inter + write (swapped: D[row=v][col=s]), two vj-halves ----
#pragma unroll
    for (int half = 0; half < 2; half++) {
        f32x4 h4[4];
#pragma unroll
        for (int j = 0; j < 4; j++) h4[j] = (f32x4){0.f, 0.f, 0.f, 0.f};

#pragma unroll
        for (int kkt = 0; kkt < 4; kkt++) {
            if (kkt <= kmax) {
#pragma unroll
                for (int j = 0; j < 4; j++) {
                    int vr = (half * 4 + j) * 16 + l15;
                    f16x8 av = *(const f16x8*)&Xb[vr * Ss + ((kkt * 32 + g * 8) ^ swt)];
                    h4[j] = __builtin_amdgcn_mfma_f32_16x16x32_f16(av, pb[kkt], h4[j], 0, 0, 0);
                }
            }
        }
#pragma unroll
        for (int j = 0; j < 4; j++) {
            int vr = (half * 4 + j) * 16 + l15;
            f32x4 tmp = {0.f, 0.f, 0.f, 0.f};
            const _Float16* cpr = cprevT + (size_t)vr * Kk + g * 8;
#pragma unroll
            for (int kk = 0; kk < 4; kk++) {
                f16x8 bcf = *(const f16x8*)(cpr + kk * 32);
                tmp = __builtin_amdgcn_mfma_f32_16x16x32_f16(bcf, qf[kk], tmp, 0, 0, 0);
            }
            float4 o;
            o.x = (h4[j][0] + tmp[0] * iw_s) * rnv_s;
            o.y = (h4[j][1] + tmp[1] * iw_s) * rnv_s;
            o.z = (h4[j][2] + tmp[2] * iw_s) * rnv_s;
            o.w = (h4[j][3] + tmp[3] * iw_s) * rnv_s;
            *(float4*)&out[(rowbase + S0 + l15) * Vv + (half * 4 + j) * 16 + 4 * g] = o;
        }
    }
}

// ---------------------------------------------------------------------------
extern "C" void kernel_launch(void* const* d_in, const int* in_sizes, int n_in,
                              void* d_out, int out_size, void* d_ws, size_t ws_size,
                              hipStream_t stream) {
    (void)in_sizes; (void)n_in; (void)out_size; (void)ws_size;
    const float* q  = (const float*)d_in[0];
    const float* k  = (const float*)d_in[1];
    const float* v  = (const float*)d_in[2];
    const float* ig = (const float*)d_in[3];
    const float* fg = (const float*)d_in[4];
    const float* C0 = (const float*)d_in[5];
    const float* n0 = (const float*)d_in[6];
    const float* m0 = (const float*)d_in[7];
    float* out = (float*)d_out;
    float* ws  = (float*)d_ws;

    k_kvg<<<BH * Cc, 512, 0, stream>>>(ig, fg, k, v, ws);
    k_scan_apply<<<(BH * Kk * Vv / 2 + BH * Kk) / 128, 128, 0, stream>>>(C0, n0, m0, ws);
    k_out_mfma<<<BH * Cc, 512, 0, stream>>>(q, k, v, ig, m0, ws, out);
}

// Round 11
// 60.673 us; speedup vs baseline: 1.1887x; 1.0421x over previous
//
#include <hip/hip_runtime.h>
#include <hip/hip_fp16.h>
#include <math.h>

#define Bb 2
#define Hh 8
#define Tt 4096
#define Kk 128
#define Vv 128
#define Ss 128
#define Cc 32
#define BH (Bb*Hh)
#define SCALE 0.08838834764831845f  /* 1/sqrt(128) */

// ---- workspace layout (float indices; ws_size ~268MB, we use ~51MB) ----
#define OFF_LFACC  0                               // BH*Tt
#define OFF_LFLAST (OFF_LFACC + BH*Tt)             // BH*Cc
#define OFF_MINTRA (OFF_LFLAST + BH*Cc)
#define OFF_KSUM   (OFF_MINTRA + BH*Cc)            // BH*Cc*Kk (fp32 -> n_prev)
#define OFF_KVH    (OFF_KSUM + BH*Cc*Kk)           // fp16 kv^T [blk][v][k] (-> c_prev^T)
#define OFF_KIMG   (OFF_KVH + BH*Cc*Kk*Vv/2)       // fp16 K image [blk][t][k^sw]
#define OFF_VIMG   (OFF_KIMG + BH*Tt*Kk/2)         // fp16 V^T image [blk][v][t^sw]

typedef _Float16 f16x8 __attribute__((ext_vector_type(8)));
typedef _Float16 f16x4 __attribute__((ext_vector_type(4)));
typedef _Float16 f16x2 __attribute__((ext_vector_type(2)));
typedef float f32x4 __attribute__((ext_vector_type(4)));

union U2 { f16x2 h; unsigned u; };
union U8 { f16x8 v; unsigned u[4]; };

#define GLDS16(gp, lp) __builtin_amdgcn_global_load_lds( \
    (const __attribute__((address_space(1))) void*)(gp), \
    (__attribute__((address_space(3))) void*)(lp), 16, 0, 0)

// ---------------------------------------------------------------------------
// Kernel 1: fused gates + MFMA kv^T (fp16) + ksum + K/V^T fp16 image export.
// 512 threads, 8 waves. Both staging reps' loads hoisted above gates.
// ---------------------------------------------------------------------------
__global__ __launch_bounds__(512, 4) void k_kvg(const float* __restrict__ ig,
                                                const float* __restrict__ fg,
                                                const float* __restrict__ kg,
                                                const float* __restrict__ vg,
                                                float* __restrict__ ws) {
    __shared__ _Float16 Kt[Ss * Ss];   // (g*K)^T [kidx][t], swizzled
    __shared__ _Float16 Vt[Ss * Ss];   // V^T [vidx][t], swizzled
    __shared__ float sfg[Ss];
    __shared__ float scomb[4];

    int blk = blockIdx.x;
    int bh = blk >> 5;
    int c  = blk & 31;
    int tid = threadIdx.x;
    int lane = tid & 63;
    int w = tid >> 6;
    int l15 = lane & 15;
    int g = lane >> 4;

    const float* kb = kg + ((size_t)bh * Tt + (size_t)c * Ss) * Kk;
    const float* vb = vg + ((size_t)bh * Tt + (size_t)c * Ss) * Vv;
    _Float16* kimgw = (_Float16*)(ws + OFF_KIMG) + (size_t)blk * Ss * Kk;
    _Float16* vimgw = (_Float16*)(ws + OFF_VIMG) + (size_t)blk * Ss * Kk;

    // ---- hoisted staging loads, BOTH reps (latency hides under gates) ----
    int c0a = (tid & 31) * 4;
    int t0a = (tid >> 5) * 4;
    const float* ksrcA = kb + (size_t)t0a * Kk + c0a;
    const float* vsrcA = vb + (size_t)t0a * Vv + c0a;
    float4 kA0 = *(const float4*)(ksrcA);
    float4 kA1 = *(const float4*)(ksrcA + Kk);
    float4 kA2 = *(const float4*)(ksrcA + 2 * Kk);
    float4 kA3 = *(const float4*)(ksrcA + 3 * Kk);
    float4 vA0 = *(const float4*)(vsrcA);
    float4 vA1 = *(const float4*)(vsrcA + Vv);
    float4 vA2 = *(const float4*)(vsrcA + 2 * Vv);
    float4 vA3 = *(const float4*)(vsrcA + 3 * Vv);
    int tau1 = tid + 512;
    int c0b = (tau1 & 31) * 4;
    int t0b = (tau1 >> 5) * 4;
    const float* ksrcB = kb + (size_t)t0b * Kk + c0b;
    const float* vsrcB = vb + (size_t)t0b * Vv + c0b;
    float4 kB0 = *(const float4*)(ksrcB);
    float4 kB1 = *(const float4*)(ksrcB + Kk);
    float4 kB2 = *(const float4*)(ksrcB + 2 * Kk);
    float4 kB3 = *(const float4*)(ksrcB + 3 * Kk);
    float4 vB0 = *(const float4*)(vsrcB);
    float4 vB1 = *(const float4*)(vsrcB + Vv);
    float4 vB2 = *(const float4*)(vsrcB + 2 * Vv);
    float4 vB3 = *(const float4*)(vsrcB + 3 * Vv);

    // ---- gates (threads 0..127, shfl-based scan) ----
    bool p0 = tid < Ss;
    int lane64 = tid & 63;
    int wv = (tid >> 6) & 1;
    int gidx = bh * Tt + c * Ss + tid;
    float lfacc = 0.f, fwd = 0.f;
    if (p0) {
        float x  = fg[gidx];
        lfacc = fminf(x, 0.f) - log1pf(__expf(-fabsf(x)));
        for (int off = 1; off < 64; off <<= 1) {
            float o = __shfl_up(lfacc, off);
            if (lane64 >= off) lfacc += o;
        }
        if (lane64 == 63) scomb[wv] = lfacc;
    }
    __syncthreads();
    if (p0) {
        float tot0 = scomb[0];
        if (wv == 1) lfacc += tot0;
        float lflast = tot0 + scomb[1];
        fwd = ig[gidx] + lflast - lfacc;
        float mx = fwd;
        for (int off = 32; off; off >>= 1) mx = fmaxf(mx, __shfl_xor(mx, off));
        if (lane64 == 0) scomb[2 + wv] = mx;
    }
    __syncthreads();
    if (p0) {
        float mi = fmaxf(scomb[2], scomb[3]);
        sfg[tid] = __expf(fwd - mi);
        ws[OFF_LFACC + gidx] = lfacc;
        if (tid == 0) {
            ws[OFF_LFLAST + blk] = scomb[0] + scomb[1];
            ws[OFF_MINTRA + blk] = mi;
        }
    }
    __syncthreads();

    // ---- K image export (raw fp16, pre-swizzled [t][k^((t&15)<<3)]) ----
#pragma unroll
    for (int jr = 0; jr < 4; jr++) {
        float4 kr4 = (jr == 0 ? kA0 : jr == 1 ? kA1 : jr == 2 ? kA2 : kA3);
        int t = t0a + jr;
        int col = c0a ^ ((t & 15) << 3);
        f16x4 h = { (_Float16)kr4.x, (_Float16)kr4.y, (_Float16)kr4.z, (_Float16)kr4.w };
        *(f16x4*)&kimgw[(size_t)t * Kk + col] = h;
    }
#pragma unroll
    for (int jr = 0; jr < 4; jr++) {
        float4 kr4 = (jr == 0 ? kB0 : jr == 1 ? kB1 : jr == 2 ? kB2 : kB3);
        int t = t0b + jr;
        int col = c0b ^ ((t & 15) << 3);
        f16x4 h = { (_Float16)kr4.x, (_Float16)kr4.y, (_Float16)kr4.z, (_Float16)kr4.w };
        *(f16x4*)&kimgw[(size_t)t * Kk + col] = h;
    }

    // ---- stage rep0 (from hoisted regs) ----
    {
        float g0 = sfg[t0a], g1 = sfg[t0a + 1], g2 = sfg[t0a + 2], g3 = sfg[t0a + 3];
#pragma unroll
        for (int jc = 0; jc < 4; jc++) {
            float ke0 = (jc == 0 ? kA0.x : jc == 1 ? kA0.y : jc == 2 ? kA0.z : kA0.w);
            float ke1 = (jc == 0 ? kA1.x : jc == 1 ? kA1.y : jc == 2 ? kA1.z : kA1.w);
            float ke2 = (jc == 0 ? kA2.x : jc == 1 ? kA2.y : jc == 2 ? kA2.z : kA2.w);
            float ke3 = (jc == 0 ? kA3.x : jc == 1 ? kA3.y : jc == 2 ? kA3.z : kA3.w);
            float ve0 = (jc == 0 ? vA0.x : jc == 1 ? vA0.y : jc == 2 ? vA0.z : vA0.w);
            float ve1 = (jc == 0 ? vA1.x : jc == 1 ? vA1.y : jc == 2 ? vA1.z : vA1.w);
            float ve2 = (jc == 0 ? vA2.x : jc == 1 ? vA2.y : jc == 2 ? vA2.z : vA2.w);
            float ve3 = (jc == 0 ? vA3.x : jc == 1 ? vA3.y : jc == 2 ? vA3.z : vA3.w);
            int row = c0a + jc;
            int col = t0a ^ ((row & 15) << 3);
            f16x4 kc = { (_Float16)(ke0 * g0), (_Float16)(ke1 * g1),
                         (_Float16)(ke2 * g2), (_Float16)(ke3 * g3) };
            f16x4 vc = { (_Float16)ve0, (_Float16)ve1, (_Float16)ve2, (_Float16)ve3 };
            *(f16x4*)&Kt[row * Ss + col] = kc;
            *(f16x4*)&Vt[row * Ss + col] = vc;
        }
    }
    // ---- stage rep1 (from hoisted regs) ----
    {
        float g0 = sfg[t0b], g1 = sfg[t0b + 1], g2 = sfg[t0b + 2], g3 = sfg[t0b + 3];
#pragma unroll
        for (int jc = 0; jc < 4; jc++) {
            float ke0 = (jc == 0 ? kB0.x : jc == 1 ? kB0.y : jc == 2 ? kB0.z : kB0.w);
            float ke1 = (jc == 0 ? kB1.x : jc == 1 ? kB1.y : jc == 2 ? kB1.z : kB1.w);
            float ke2 = (jc == 0 ? kB2.x : jc == 1 ? kB2.y : jc == 2 ? kB2.z : kB2.w);
            float ke3 = (jc == 0 ? kB3.x : jc == 1 ? kB3.y : jc == 2 ? kB3.z : kB3.w);
            float ve0 = (jc == 0 ? vB0.x : jc == 1 ? vB0.y : jc == 2 ? vB0.z : vB0.w);
            float ve1 = (jc == 0 ? vB1.x : jc == 1 ? vB1.y : jc == 2 ? vB1.z : vB1.w);
            float ve2 = (jc == 0 ? vB2.x : jc == 1 ? vB2.y : jc == 2 ? vB2.z : vB2.w);
            float ve3 = (jc == 0 ? vB3.x : jc == 1 ? vB3.y : jc == 2 ? vB3.z : vB3.w);
            int row = c0b + jc;
            int col = t0b ^ ((row & 15) << 3);
            f16x4 kc = { (_Float16)(ke0 * g0), (_Float16)(ke1 * g1),
                         (_Float16)(ke2 * g2), (_Float16)(ke3 * g3) };
            f16x4 vc = { (_Float16)ve0, (_Float16)ve1, (_Float16)ve2, (_Float16)ve3 };
            *(f16x4*)&Kt[row * Ss + col] = kc;
            *(f16x4*)&Vt[row * Ss + col] = vc;
        }
    }
    __syncthreads();

    // ---- V^T image export (verbatim swizzled dump; overlaps MFMA below) ----
#pragma unroll
    for (int p = 0; p < 4; p++)
        *(f16x8*)&vimgw[(size_t)(p * 512 + tid) * 8] =
            *(const f16x8*)&Vt[(p * 512 + tid) * 8];

    // ---- ksum: per-row reduction of Kt (threads 0..127) ----
    if (tid < Ss) {
        int sw = (tid & 15) << 3;
        float s = 0.f;
#pragma unroll
        for (int i = 0; i < 16; i++) {
            f16x8 ld = *(const f16x8*)&Kt[tid * Ss + ((8 * i) ^ sw)];
#pragma unroll
            for (int e = 0; e < 8; e++) s += (float)ld[e];
        }
        ws[OFF_KSUM + (size_t)blk * Kk + tid] = s;
    }

    // ---- MFMA (swapped): wave w -> vidx band [16w, 16w+16) ----
    const int band = w * 16;
    const int swt = l15 << 3;
    f16x8 af[4];
#pragma unroll
    for (int kk = 0; kk < 4; kk++)
        af[kk] = *(const f16x8*)&Vt[(band + l15) * Ss + ((kk * 32 + g * 8) ^ swt)];

    f32x4 acc[8];
#pragma unroll
    for (int kj = 0; kj < 8; kj++) acc[kj] = (f32x4){0.f, 0.f, 0.f, 0.f};

#pragma unroll
    for (int kj = 0; kj < 8; kj++) {
        int kr = kj * 16 + l15;
#pragma unroll
        for (int kk = 0; kk < 4; kk++) {
            f16x8 bv = *(const f16x8*)&Kt[kr * Ss + ((kk * 32 + g * 8) ^ swt)];
            acc[kj] = __builtin_amdgcn_mfma_f32_16x16x32_f16(af[kk], bv, acc[kj], 0, 0, 0);
        }
    }

    _Float16* dst = (_Float16*)(ws + OFF_KVH) + (size_t)blk * Kk * Vv;
#pragma unroll
    for (int kj = 0; kj < 8; kj++)
#pragma unroll
        for (int r = 0; r < 4; r++)
            dst[(size_t)(band + 4 * g + r) * Kk + kj * 16 + l15] = (_Float16)acc[kj][r];
}

// ---------------------------------------------------------------------------
// Kernel 2: scan application; coefficients computed block-locally.
// ---------------------------------------------------------------------------
__global__ __launch_bounds__(128) void k_scan_apply(const float* __restrict__ C0,
                                                    const float* __restrict__ n0,
                                                    const float* __restrict__ m0,
                                                    float* __restrict__ ws) {
    __shared__ float se1[Cc], se2[Cc];
    const int NC2 = BH * Kk * Vv / 2;     // 131072 f16x2 elements
    int gid = blockIdx.x * 128 + threadIdx.x;
    bool main_r = gid < NC2;
    int bh = main_r ? (gid >> 13) : ((gid - NC2) >> 7);

    if (threadIdx.x < Cc) {
        int cc = threadIdx.x;
        float m   = m0[bh];
        float lfl = ws[OFF_LFLAST + bh * Cc + cc];
        float mi  = ws[OFF_MINTRA + bh * Cc + cc];
        float mn  = fmaxf(lfl + m, mi);
        se1[cc] = __expf(lfl + m - mn);
        se2[cc] = __expf(mi - mn);
    }
    __syncthreads();

    if (main_r) {
        int i  = gid & 8191;
        int v  = i >> 6;
        int k2 = (i & 63) << 1;
        float st0 = C0[(size_t)bh * Kk * Vv + (size_t)k2 * Vv + v];
        float st1 = C0[(size_t)bh * Kk * Vv + (size_t)(k2 + 1) * Vv + v];
        f16x2* base = (f16x2*)((_Float16*)(ws + OFF_KVH) +
                               (size_t)bh * Cc * Kk * Vv + (size_t)v * Kk + k2);
        const size_t stride = Kk * Vv / 2;
        f16x2 cur = base[0];
        f16x2 nxt = base[stride];
#pragma unroll
        for (int c = 0; c < Cc; c++) {
            f16x2 n2 = (c + 2 < Cc) ? base[(size_t)(c + 2) * stride]
                                    : (f16x2){(_Float16)0.f, (_Float16)0.f};
            f16x2 o = { (_Float16)st0, (_Float16)st1 };
            base[(size_t)c * stride] = o;          // c_prev^T for chunk c
            float e1 = se1[c], e2 = se2[c];
            st0 = st0 * e1 + (float)cur[0] * e2;
            st1 = st1 * e1 + (float)cur[1] * e2;
            cur = nxt; nxt = n2;
        }
    } else if (gid < NC2 + BH * Kk) {
        int g2 = gid - NC2;
        float st = n0[g2];
        float* base = ws + OFF_KSUM + (size_t)bh * Cc * Kk + (g2 & (Kk - 1));
        float cur = base[0];
        float nxt = base[Kk];
#pragma unroll
        for (int c = 0; c < Cc; c++) {
            float n2 = (c + 2 < Cc) ? base[(size_t)(c + 2) * Kk] : 0.f;
            float kvv = cur;
            base[(size_t)c * Kk] = st;             // n_prev for chunk c
            st = st * se1[c] + kvv * se2[c];
            cur = nxt; nxt = n2;
        }
    }
}

// ---------------------------------------------------------------------------
// Kernel 3 (v6): K/V^T pulled via global_load_lds from pre-swizzled fp16
// images (zero staging VALU, no transpose phase). 2 barriers. M_norm fully
// in registers. Swapped QK^T (P lane-local) + swapped PV (float4 stores).
// ---------------------------------------------------------------------------
__global__ __launch_bounds__(512, 4) void k_out_mfma(const float* __restrict__ qg,
                                                     const float* __restrict__ ig,
                                                     const float* __restrict__ m0,
                                                     float* __restrict__ ws,
                                                     float* __restrict__ out) {
    __shared__ _Float16 XbK[Ss * Kk];   // K image [t][k^sw]
    __shared__ _Float16 XbV[Ss * Kk];   // V^T image [v][t^sw]
    __shared__ float sbt[Ss], sas[Ss], siw[Ss], slfa[Ss], snp[Ss];
    __shared__ float scomb[2];

    int blk = blockIdx.x;
    int bh = blk >> 5;
    int c  = blk & 31;
    int tid = threadIdx.x;
    int lane = tid & 63;
    int w = tid >> 6;                   // wave id 0..7; owns s in [16w,16w+16)
    int l15 = lane & 15;
    int g = lane >> 4;                  // 0..3
    const int S0 = w * 16;
    const int swt = l15 << 3;

    const size_t rowbase = (size_t)bh * Tt + (size_t)c * Ss;
    const float* qp = qg + rowbase * Kk;
    const float* nprev = ws + OFF_KSUM + (size_t)blk * Kk;
    const _Float16* cprevT = (const _Float16*)(ws + OFF_KVH) + (size_t)blk * Kk * Vv;
    const _Float16* kimg = (const _Float16*)(ws + OFF_KIMG) + (size_t)blk * Ss * Kk;
    const _Float16* vimg = (const _Float16*)(ws + OFF_VIMG) + (size_t)blk * Ss * Kk;
    const float m_prev = m0[bh];        // reference quirk: m never rebinds

    // ---- async image loads: HBM -> LDS, 16B/lane, wave-uniform LDS base ----
#pragma unroll
    for (int p = 0; p < 4; p++) {
        int unit = p * 512 + w * 64;                 // wave-uniform
        GLDS16(kimg + (size_t)(unit + lane) * 8, &XbK[unit * 8]);
        GLDS16(vimg + (size_t)(unit + lane) * 8, &XbV[unit * 8]);
    }

    // ---- Q fragments: qf[kk][e] = q[S0+l15][kk*32+g*8+e] ----
    f16x8 qf[4];
#pragma unroll
    for (int kk = 0; kk < 4; kk++) {
        const float* p = qp + (size_t)(S0 + l15) * Kk + kk * 32 + g * 8;
        float4 a = *(const float4*)p;
        float4 b = *(const float4*)(p + 4);
        f16x8 r;
        r[0]=(_Float16)a.x; r[1]=(_Float16)a.y; r[2]=(_Float16)a.z; r[3]=(_Float16)a.w;
        r[4]=(_Float16)b.x; r[5]=(_Float16)b.y; r[6]=(_Float16)b.z; r[7]=(_Float16)b.w;
        qf[kk] = r;
    }

    // ---- phase 0 part 1: bt + prefix max (threads 0..127) ----
    bool p0 = tid < Ss;
    int lane64 = tid & 63;
    int wv = (tid >> 6) & 1;
    float pm = 0.f;
    if (p0) {
        float lfa = ws[OFF_LFACC + bh * Tt + c * Ss + tid];
        float bt = ig[bh * Tt + c * Ss + tid] - lfa;
        sbt[tid] = bt;
        slfa[tid] = lfa;
        snp[tid] = nprev[tid];
        pm = bt;
        for (int off = 1; off < 64; off <<= 1) {
            float o = __shfl_up(pm, off);
            if (lane64 >= off) pm = fmaxf(pm, o);
        }
        if (lane64 == 63) scomb[wv] = pm;
    }
    __syncthreads();   // barrier A: images in LDS, sbt/slfa/snp/scomb ready

    if (p0) {
        if (wv == 1) pm = fmaxf(pm, scomb[0]);
        float mx = fmaxf(pm, m_prev);
        sas[tid] = -mx;
        siw[tid] = SCALE * __expf(m_prev - mx);
    }
    // intern raw dot: q[s].n_prev, s = S0+l15
    float dotq = 0.f;
#pragma unroll
    for (int kk = 0; kk < 4; kk++)
#pragma unroll
        for (int e = 0; e < 8; e++)
            dotq += (float)qf[kk][e] * snp[kk * 32 + g * 8 + e];
    dotq += __shfl_xor(dotq, 16);
    dotq += __shfl_xor(dotq, 32);
    __syncthreads();   // barrier B: sas/siw ready

    const float as_s = sas[S0 + l15];
    const float iw_s = siw[S0 + l15];
    const float lfa_s = slfa[S0 + l15];

    // ---- swapped QK^T: lane gets P[s=S0+l15][t=16tj+4g+r] ----
    unsigned plo[8] = {0,0,0,0,0,0,0,0};
    unsigned phi[8] = {0,0,0,0,0,0,0,0};
    float rs = 0.f;
#pragma unroll
    for (int tj = 0; tj < 8; tj++) {
        if (tj <= w) {
            int trow = tj * 16 + l15;
            f16x8 bfr[4];
#pragma unroll
            for (int kk = 0; kk < 4; kk++)
                bfr[kk] = *(const f16x8*)&XbK[trow * Kk + ((kk * 32 + g * 8) ^ swt)];
            f32x4 acc = {0.f, 0.f, 0.f, 0.f};
#pragma unroll
            for (int kk = 0; kk < 4; kk++)
                acc = __builtin_amdgcn_mfma_f32_16x16x32_f16(bfr[kk], qf[kk], acc, 0, 0, 0);
            float vals[4];
#pragma unroll
            for (int r = 0; r < 4; r++) {
                int t = tj * 16 + 4 * g + r;
                float btv = sbt[t];
                float val = acc[r] * SCALE * __expf(as_s + btv);
                if (tj == w && (4 * g + r) > l15) val = 0.f;   // causal mask
                rs += val;
                vals[r] = val;
            }
            U2 lo, hi;
            lo.h = (f16x2){ (_Float16)vals[0], (_Float16)vals[1] };
            hi.h = (f16x2){ (_Float16)vals[2], (_Float16)vals[3] };
            plo[tj] = lo.u;
            phi[tj] = hi.u;
        }
    }
    // full row sum + M_norm, all in registers (every lane has rs/dotq)
    rs += __shfl_xor(rs, 16);
    rs += __shfl_xor(rs, 32);
    float engs = __expf(as_s - lfa_s);              // exp(-(lfa+mx))
    float rnv_s = 1.0f / fmaxf(fabsf(rs + dotq * iw_s), engs);

    // ---- P -> B-operand fragments via cross-g shfl exchange ----
    f16x8 pb[4];
    const int kmax = w >> 1;
    {
        int a2 = (g & 1) * 2;
        int sA = a2 * 16 + l15;
        int sB = sA + 16;
        bool hi2 = (g >> 1) != 0;
#pragma unroll
        for (int kkt = 0; kkt < 4; kkt++) {
            if (kkt <= kmax) {
                unsigned xA0 = __shfl((int)plo[2*kkt],   sA);
                unsigned xA1 = __shfl((int)phi[2*kkt],   sA);
                unsigned xB0 = __shfl((int)plo[2*kkt],   sB);
                unsigned xB1 = __shfl((int)phi[2*kkt],   sB);
                unsigned yA0 = __shfl((int)plo[2*kkt+1], sA);
                unsigned yA1 = __shfl((int)phi[2*kkt+1], sA);
                unsigned yB0 = __shfl((int)plo[2*kkt+1], sB);
                unsigned yB1 = __shfl((int)phi[2*kkt+1], sB);
                U8 t;
                t.u[0] = hi2 ? yA0 : xA0;
                t.u[1] = hi2 ? yA1 : xA1;
                t.u[2] = hi2 ? yB0 : xB0;
                t.u[3] = hi2 ? yB1 : xB1;
                pb[kkt] = t.v;
            }
        }
    }

    // ---- PV + inter + write (swapped: D[row=v][col=s]), two vj-halves ----
#pragma unroll
    for (int half = 0; half < 2; half++) {
        f32x4 h4[4];
#pragma unroll
        for (int j = 0; j < 4; j++) h4[j] = (f32x4){0.f, 0.f, 0.f, 0.f};

#pragma unroll
        for (int kkt = 0; kkt < 4; kkt++) {
            if (kkt <= kmax) {
#pragma unroll
                for (int j = 0; j < 4; j++) {
                    int vr = (half * 4 + j) * 16 + l15;
                    f16x8 av = *(const f16x8*)&XbV[vr * Ss + ((kkt * 32 + g * 8) ^ swt)];
                    h4[j] = __builtin_amdgcn_mfma_f32_16x16x32_f16(av, pb[kkt], h4[j], 0, 0, 0);
                }
            }
        }
#pragma unroll
        for (int j = 0; j < 4; j++) {
            int vr = (half * 4 + j) * 16 + l15;
            f32x4 tmp = {0.f, 0.f, 0.f, 0.f};
            const _Float16* cpr = cprevT + (size_t)vr * Kk + g * 8;
#pragma unroll
            for (int kk = 0; kk < 4; kk++) {
                f16x8 bcf = *(const f16x8*)(cpr + kk * 32);
                tmp = __builtin_amdgcn_mfma_f32_16x16x32_f16(bcf, qf[kk], tmp, 0, 0, 0);
            }
            float4 o;
            o.x = (h4[j][0] + tmp[0] * iw_s) * rnv_s;
            o.y = (h4[j][1] + tmp[1] * iw_s) * rnv_s;
            o.z = (h4[j][2] + tmp[2] * iw_s) * rnv_s;
            o.w = (h4[j][3] + tmp[3] * iw_s) * rnv_s;
            *(float4*)&out[(rowbase + S0 + l15) * Vv + (half * 4 + j) * 16 + 4 * g] = o;
        }
    }
}

// ---------------------------------------------------------------------------
extern "C" void kernel_launch(void* const* d_in, const int* in_sizes, int n_in,
                              void* d_out, int out_size, void* d_ws, size_t ws_size,
                              hipStream_t stream) {
    (void)in_sizes; (void)n_in; (void)out_size; (void)ws_size;
    const float* q  = (const float*)d_in[0];
    const float* k  = (const float*)d_in[1];
    const float* v  = (const float*)d_in[2];
    const float* ig = (const float*)d_in[3];
    const float* fg = (const float*)d_in[4];
    const float* C0 = (const float*)d_in[5];
    const float* n0 = (const float*)d_in[6];
    const float* m0 = (const float*)d_in[7];
    float* out = (float*)d_out;
    float* ws  = (float*)d_ws;

    k_kvg<<<BH * Cc, 512, 0, stream>>>(ig, fg, k, v, ws);
    k_scan_apply<<<(BH * Kk * Vv / 2 + BH * Kk) / 128, 128, 0, stream>>>(C0, n0, m0, ws);
    k_out_mfma<<<BH * Cc, 512, 0, stream>>>(q, ig, m0, ws, out);
}

// Round 12
// 53.081 us; speedup vs baseline: 1.3587x; 1.1430x over previous
//
#include <hip/hip_runtime.h>
#include <hip/hip_fp16.h>
#include <math.h>

#define Bb 2
#define Hh 8
#define Tt 4096
#define Kk 128
#define Vv 128
#define Ss 128
#define Cc 32
#define BH (Bb*Hh)
#define SCALE 0.08838834764831845f  /* 1/sqrt(128) */

// ---- workspace layout (float indices) ----
#define OFF_LFACC  0                               // BH*Tt
#define OFF_LFLAST (OFF_LFACC + BH*Tt)             // BH*Cc
#define OFF_MINTRA (OFF_LFLAST + BH*Cc)
#define OFF_KSUM   (OFF_MINTRA + BH*Cc)            // BH*Cc*Kk (fp32 -> n_prev)
#define OFF_KVH    (OFF_KSUM + BH*Cc*Kk)           // fp16 kv^T [blk][v][k^sw] SWIZZLED
#define OFF_KIMG   (OFF_KVH + BH*Cc*Kk*Vv/2)       // fp16 K image [blk][t][k^sw]
#define OFF_VIMG   (OFF_KIMG + BH*Tt*Kk/2)         // fp16 V^T image [blk][v][t^sw]

typedef _Float16 f16x8 __attribute__((ext_vector_type(8)));
typedef _Float16 f16x4 __attribute__((ext_vector_type(4)));
typedef _Float16 f16x2 __attribute__((ext_vector_type(2)));
typedef float f32x4 __attribute__((ext_vector_type(4)));

union U2 { f16x2 h; unsigned u; };
union U8 { f16x8 v; unsigned u[4]; };

#define GLDS16(gp, lp) __builtin_amdgcn_global_load_lds( \
    (const __attribute__((address_space(1))) void*)(gp), \
    (__attribute__((address_space(3))) void*)(lp), 16, 0, 0)

// ---------------------------------------------------------------------------
// Kernel 1: fused gates + MFMA kv^T (fp16, swizzled) + ksum + K/V^T images.
// 512 threads, 8 waves. All staging loads hoisted; kimg export above gates.
// ---------------------------------------------------------------------------
__global__ __launch_bounds__(512, 4) void k_kvg(const float* __restrict__ ig,
                                                const float* __restrict__ fg,
                                                const float* __restrict__ kg,
                                                const float* __restrict__ vg,
                                                float* __restrict__ ws) {
    __shared__ _Float16 Kt[Ss * Ss];   // (g*K)^T [kidx][t], swizzled
    __shared__ _Float16 Vt[Ss * Ss];   // V^T [vidx][t], swizzled
    __shared__ float sfg[Ss];
    __shared__ float scomb[4];

    int blk = blockIdx.x;
    int bh = blk >> 5;
    int c  = blk & 31;
    int tid = threadIdx.x;
    int lane = tid & 63;
    int w = tid >> 6;
    int l15 = lane & 15;
    int g = lane >> 4;

    const float* kb = kg + ((size_t)bh * Tt + (size_t)c * Ss) * Kk;
    const float* vb = vg + ((size_t)bh * Tt + (size_t)c * Ss) * Vv;
    _Float16* kimgw = (_Float16*)(ws + OFF_KIMG) + (size_t)blk * Ss * Kk;
    _Float16* vimgw = (_Float16*)(ws + OFF_VIMG) + (size_t)blk * Ss * Kk;

    // ---- hoisted staging loads, BOTH reps ----
    int c0a = (tid & 31) * 4;
    int t0a = (tid >> 5) * 4;
    const float* ksrcA = kb + (size_t)t0a * Kk + c0a;
    const float* vsrcA = vb + (size_t)t0a * Vv + c0a;
    float4 kA0 = *(const float4*)(ksrcA);
    float4 kA1 = *(const float4*)(ksrcA + Kk);
    float4 kA2 = *(const float4*)(ksrcA + 2 * Kk);
    float4 kA3 = *(const float4*)(ksrcA + 3 * Kk);
    float4 vA0 = *(const float4*)(vsrcA);
    float4 vA1 = *(const float4*)(vsrcA + Vv);
    float4 vA2 = *(const float4*)(vsrcA + 2 * Vv);
    float4 vA3 = *(const float4*)(vsrcA + 3 * Vv);
    int tau1 = tid + 512;
    int c0b = (tau1 & 31) * 4;
    int t0b = (tau1 >> 5) * 4;
    const float* ksrcB = kb + (size_t)t0b * Kk + c0b;
    const float* vsrcB = vb + (size_t)t0b * Vv + c0b;
    float4 kB0 = *(const float4*)(ksrcB);
    float4 kB1 = *(const float4*)(ksrcB + Kk);
    float4 kB2 = *(const float4*)(ksrcB + 2 * Kk);
    float4 kB3 = *(const float4*)(ksrcB + 3 * Kk);
    float4 vB0 = *(const float4*)(vsrcB);
    float4 vB1 = *(const float4*)(vsrcB + Vv);
    float4 vB2 = *(const float4*)(vsrcB + 2 * Vv);
    float4 vB3 = *(const float4*)(vsrcB + 3 * Vv);

    // ---- K image export (pre-swizzled [t][k^((t&15)<<3)]) — above gates ----
#pragma unroll
    for (int jr = 0; jr < 4; jr++) {
        float4 kr4 = (jr == 0 ? kA0 : jr == 1 ? kA1 : jr == 2 ? kA2 : kA3);
        int t = t0a + jr;
        int col = c0a ^ ((t & 15) << 3);
        f16x4 h = { (_Float16)kr4.x, (_Float16)kr4.y, (_Float16)kr4.z, (_Float16)kr4.w };
        *(f16x4*)&kimgw[(size_t)t * Kk + col] = h;
    }
#pragma unroll
    for (int jr = 0; jr < 4; jr++) {
        float4 kr4 = (jr == 0 ? kB0 : jr == 1 ? kB1 : jr == 2 ? kB2 : kB3);
        int t = t0b + jr;
        int col = c0b ^ ((t & 15) << 3);
        f16x4 h = { (_Float16)kr4.x, (_Float16)kr4.y, (_Float16)kr4.z, (_Float16)kr4.w };
        *(f16x4*)&kimgw[(size_t)t * Kk + col] = h;
    }

    // ---- gates (threads 0..127, shfl-based scan) ----
    bool p0 = tid < Ss;
    int lane64 = tid & 63;
    int wv = (tid >> 6) & 1;
    int gidx = bh * Tt + c * Ss + tid;
    float lfacc = 0.f, fwd = 0.f;
    if (p0) {
        float x  = fg[gidx];
        lfacc = fminf(x, 0.f) - log1pf(__expf(-fabsf(x)));
        for (int off = 1; off < 64; off <<= 1) {
            float o = __shfl_up(lfacc, off);
            if (lane64 >= off) lfacc += o;
        }
        if (lane64 == 63) scomb[wv] = lfacc;
    }
    __syncthreads();
    if (p0) {
        float tot0 = scomb[0];
        if (wv == 1) lfacc += tot0;
        float lflast = tot0 + scomb[1];
        fwd = ig[gidx] + lflast - lfacc;
        float mx = fwd;
        for (int off = 32; off; off >>= 1) mx = fmaxf(mx, __shfl_xor(mx, off));
        if (lane64 == 0) scomb[2 + wv] = mx;
    }
    __syncthreads();
    if (p0) {
        float mi = fmaxf(scomb[2], scomb[3]);
        sfg[tid] = __expf(fwd - mi);
        ws[OFF_LFACC + gidx] = lfacc;
        if (tid == 0) {
            ws[OFF_LFLAST + blk] = scomb[0] + scomb[1];
            ws[OFF_MINTRA + blk] = mi;
        }
    }
    __syncthreads();

    // ---- stage rep0 ----
    {
        float g0 = sfg[t0a], g1 = sfg[t0a + 1], g2 = sfg[t0a + 2], g3 = sfg[t0a + 3];
#pragma unroll
        for (int jc = 0; jc < 4; jc++) {
            float ke0 = (jc == 0 ? kA0.x : jc == 1 ? kA0.y : jc == 2 ? kA0.z : kA0.w);
            float ke1 = (jc == 0 ? kA1.x : jc == 1 ? kA1.y : jc == 2 ? kA1.z : kA1.w);
            float ke2 = (jc == 0 ? kA2.x : jc == 1 ? kA2.y : jc == 2 ? kA2.z : kA2.w);
            float ke3 = (jc == 0 ? kA3.x : jc == 1 ? kA3.y : jc == 2 ? kA3.z : kA3.w);
            float ve0 = (jc == 0 ? vA0.x : jc == 1 ? vA0.y : jc == 2 ? vA0.z : vA0.w);
            float ve1 = (jc == 0 ? vA1.x : jc == 1 ? vA1.y : jc == 2 ? vA1.z : vA1.w);
            float ve2 = (jc == 0 ? vA2.x : jc == 1 ? vA2.y : jc == 2 ? vA2.z : vA2.w);
            float ve3 = (jc == 0 ? vA3.x : jc == 1 ? vA3.y : jc == 2 ? vA3.z : vA3.w);
            int row = c0a + jc;
            int col = t0a ^ ((row & 15) << 3);
            f16x4 kc = { (_Float16)(ke0 * g0), (_Float16)(ke1 * g1),
                         (_Float16)(ke2 * g2), (_Float16)(ke3 * g3) };
            f16x4 vc = { (_Float16)ve0, (_Float16)ve1, (_Float16)ve2, (_Float16)ve3 };
            *(f16x4*)&Kt[row * Ss + col] = kc;
            *(f16x4*)&Vt[row * Ss + col] = vc;
        }
    }
    // ---- stage rep1 ----
    {
        float g0 = sfg[t0b], g1 = sfg[t0b + 1], g2 = sfg[t0b + 2], g3 = sfg[t0b + 3];
#pragma unroll
        for (int jc = 0; jc < 4; jc++) {
            float ke0 = (jc == 0 ? kB0.x : jc == 1 ? kB0.y : jc == 2 ? kB0.z : kB0.w);
            float ke1 = (jc == 0 ? kB1.x : jc == 1 ? kB1.y : jc == 2 ? kB1.z : kB1.w);
            float ke2 = (jc == 0 ? kB2.x : jc == 1 ? kB2.y : jc == 2 ? kB2.z : kB2.w);
            float ke3 = (jc == 0 ? kB3.x : jc == 1 ? kB3.y : jc == 2 ? kB3.z : kB3.w);
            float ve0 = (jc == 0 ? vB0.x : jc == 1 ? vB0.y : jc == 2 ? vB0.z : vB0.w);
            float ve1 = (jc == 0 ? vB1.x : jc == 1 ? vB1.y : jc == 2 ? vB1.z : vB1.w);
            float ve2 = (jc == 0 ? vB2.x : jc == 1 ? vB2.y : jc == 2 ? vB2.z : vB2.w);
            float ve3 = (jc == 0 ? vB3.x : jc == 1 ? vB3.y : jc == 2 ? vB3.z : vB3.w);
            int row = c0b + jc;
            int col = t0b ^ ((row & 15) << 3);
            f16x4 kc = { (_Float16)(ke0 * g0), (_Float16)(ke1 * g1),
                         (_Float16)(ke2 * g2), (_Float16)(ke3 * g3) };
            f16x4 vc = { (_Float16)ve0, (_Float16)ve1, (_Float16)ve2, (_Float16)ve3 };
            *(f16x4*)&Kt[row * Ss + col] = kc;
            *(f16x4*)&Vt[row * Ss + col] = vc;
        }
    }
    __syncthreads();

    // ---- V^T image export (verbatim swizzled dump) ----
#pragma unroll
    for (int p = 0; p < 4; p++)
        *(f16x8*)&vimgw[(size_t)(p * 512 + tid) * 8] =
            *(const f16x8*)&Vt[(p * 512 + tid) * 8];

    // ---- ksum: per-row reduction of Kt (threads 0..127) ----
    if (tid < Ss) {
        int sw = (tid & 15) << 3;
        float s = 0.f;
#pragma unroll
        for (int i = 0; i < 16; i++) {
            f16x8 ld = *(const f16x8*)&Kt[tid * Ss + ((8 * i) ^ sw)];
#pragma unroll
            for (int e = 0; e < 8; e++) s += (float)ld[e];
        }
        ws[OFF_KSUM + (size_t)blk * Kk + tid] = s;
    }

    // ---- MFMA (swapped): wave w -> vidx band [16w, 16w+16) ----
    const int band = w * 16;
    const int swt = l15 << 3;
    f16x8 af[4];
#pragma unroll
    for (int kk = 0; kk < 4; kk++)
        af[kk] = *(const f16x8*)&Vt[(band + l15) * Ss + ((kk * 32 + g * 8) ^ swt)];

    f32x4 acc[8];
#pragma unroll
    for (int kj = 0; kj < 8; kj++) acc[kj] = (f32x4){0.f, 0.f, 0.f, 0.f};

#pragma unroll
    for (int kj = 0; kj < 8; kj++) {
        int kr = kj * 16 + l15;
#pragma unroll
        for (int kk = 0; kk < 4; kk++) {
            f16x8 bv = *(const f16x8*)&Kt[kr * Ss + ((kk * 32 + g * 8) ^ swt)];
            acc[kj] = __builtin_amdgcn_mfma_f32_16x16x32_f16(af[kk], bv, acc[kj], 0, 0, 0);
        }
    }

    // ---- write kv^T fp16, SWIZZLED [v][k ^ ((v&15)<<3)] ----
    _Float16* dst = (_Float16*)(ws + OFF_KVH) + (size_t)blk * Kk * Vv;
#pragma unroll
    for (int kj = 0; kj < 8; kj++)
#pragma unroll
        for (int r = 0; r < 4; r++) {
            int vrow = band + 4 * g + r;
            int col = (kj * 16 + l15) ^ ((vrow & 15) << 3);
            dst[(size_t)vrow * Kk + col] = (_Float16)acc[kj][r];
        }
}

// ---------------------------------------------------------------------------
// Kernel 2: scan application on SWIZZLED kv^T (in-place chains are layout-
// invariant; only the C0 seed needs the inverse swizzle). Coefficients
// computed block-locally.
// ---------------------------------------------------------------------------
__global__ __launch_bounds__(128) void k_scan_apply(const float* __restrict__ C0,
                                                    const float* __restrict__ n0,
                                                    const float* __restrict__ m0,
                                                    float* __restrict__ ws) {
    __shared__ float se1[Cc], se2[Cc];
    const int NC2 = BH * Kk * Vv / 2;     // 131072 f16x2 elements
    int gid = blockIdx.x * 128 + threadIdx.x;
    bool main_r = gid < NC2;
    int bh = main_r ? (gid >> 13) : ((gid - NC2) >> 7);

    if (threadIdx.x < Cc) {
        int cc = threadIdx.x;
        float m   = m0[bh];
        float lfl = ws[OFF_LFLAST + bh * Cc + cc];
        float mi  = ws[OFF_MINTRA + bh * Cc + cc];
        float mn  = fmaxf(lfl + m, mi);
        se1[cc] = __expf(lfl + m - mn);
        se2[cc] = __expf(mi - mn);
    }
    __syncthreads();

    if (main_r) {
        int i  = gid & 8191;
        int v  = i >> 6;
        int j2 = (i & 63) << 1;                 // stored position (even)
        int klog = j2 ^ ((v & 15) << 3);        // logical k at this position
        float st0 = C0[(size_t)bh * Kk * Vv + (size_t)klog * Vv + v];
        float st1 = C0[(size_t)bh * Kk * Vv + (size_t)(klog + 1) * Vv + v];
        f16x2* base = (f16x2*)((_Float16*)(ws + OFF_KVH) +
                               (size_t)bh * Cc * Kk * Vv + (size_t)v * Kk + j2);
        const size_t stride = Kk * Vv / 2;
        f16x2 cur = base[0];
        f16x2 nxt = base[stride];
#pragma unroll
        for (int c = 0; c < Cc; c++) {
            f16x2 n2 = (c + 2 < Cc) ? base[(size_t)(c + 2) * stride]
                                    : (f16x2){(_Float16)0.f, (_Float16)0.f};
            f16x2 o = { (_Float16)st0, (_Float16)st1 };
            base[(size_t)c * stride] = o;          // c_prev^T for chunk c
            float e1 = se1[c], e2 = se2[c];
            st0 = st0 * e1 + (float)cur[0] * e2;
            st1 = st1 * e1 + (float)cur[1] * e2;
            cur = nxt; nxt = n2;
        }
    } else if (gid < NC2 + BH * Kk) {
        int g2 = gid - NC2;
        float st = n0[g2];
        float* base = ws + OFF_KSUM + (size_t)bh * Cc * Kk + (g2 & (Kk - 1));
        float cur = base[0];
        float nxt = base[Kk];
#pragma unroll
        for (int c = 0; c < Cc; c++) {
            float n2 = (c + 2 < Cc) ? base[(size_t)(c + 2) * Kk] : 0.f;
            float kvv = cur;
            base[(size_t)c * Kk] = st;             // n_prev for chunk c
            st = st * se1[c] + kvv * se2[c];
            cur = nxt; nxt = n2;
        }
    }
}

// ---------------------------------------------------------------------------
// Kernel 3 (v7): after QK^T, XbK is dead — stage c_prev^T into it via
// global_load_lds (issued at barrier C, latency hidden under pb-shuffles +
// the whole PV phase), then inter MFMAs read LDS conflict-free. Eliminates
// the 8x-duplicated direct-global c_prev reads (32 serial loads/thread).
// ---------------------------------------------------------------------------
__global__ __launch_bounds__(512, 4) void k_out_mfma(const float* __restrict__ qg,
                                                     const float* __restrict__ ig,
                                                     const float* __restrict__ m0,
                                                     float* __restrict__ ws,
                                                     float* __restrict__ out) {
    __shared__ _Float16 XbK[Ss * Kk];   // K image [t][k^sw]; later c_prev^T
    __shared__ _Float16 XbV[Ss * Kk];   // V^T image [v][t^sw]
    __shared__ float sbt[Ss], sas[Ss], siw[Ss], slfa[Ss], snp[Ss];
    __shared__ float scomb[2];

    int blk = blockIdx.x;
    int bh = blk >> 5;
    int c  = blk & 31;
    int tid = threadIdx.x;
    int lane = tid & 63;
    int w = tid >> 6;                   // wave id 0..7; owns s in [16w,16w+16)
    int l15 = lane & 15;
    int g = lane >> 4;                  // 0..3
    const int S0 = w * 16;
    const int swt = l15 << 3;

    const size_t rowbase = (size_t)bh * Tt + (size_t)c * Ss;
    const float* qp = qg + rowbase * Kk;
    const float* nprev = ws + OFF_KSUM + (size_t)blk * Kk;
    const _Float16* cprevT = (const _Float16*)(ws + OFF_KVH) + (size_t)blk * Kk * Vv;
    const _Float16* kimg = (const _Float16*)(ws + OFF_KIMG) + (size_t)blk * Ss * Kk;
    const _Float16* vimg = (const _Float16*)(ws + OFF_VIMG) + (size_t)blk * Ss * Kk;
    const float m_prev = m0[bh];        // reference quirk: m never rebinds

    // ---- async image loads: HBM -> LDS, 16B/lane, wave-uniform LDS base ----
#pragma unroll
    for (int p = 0; p < 4; p++) {
        int unit = p * 512 + w * 64;                 // wave-uniform
        GLDS16(kimg + (size_t)(unit + lane) * 8, &XbK[unit * 8]);
        GLDS16(vimg + (size_t)(unit + lane) * 8, &XbV[unit * 8]);
    }

    // ---- Q fragments: qf[kk][e] = q[S0+l15][kk*32+g*8+e] ----
    f16x8 qf[4];
#pragma unroll
    for (int kk = 0; kk < 4; kk++) {
        const float* p = qp + (size_t)(S0 + l15) * Kk + kk * 32 + g * 8;
        float4 a = *(const float4*)p;
        float4 b = *(const float4*)(p + 4);
        f16x8 r;
        r[0]=(_Float16)a.x; r[1]=(_Float16)a.y; r[2]=(_Float16)a.z; r[3]=(_Float16)a.w;
        r[4]=(_Float16)b.x; r[5]=(_Float16)b.y; r[6]=(_Float16)b.z; r[7]=(_Float16)b.w;
        qf[kk] = r;
    }

    // ---- phase 0 part 1: bt + prefix max (threads 0..127) ----
    bool p0 = tid < Ss;
    int lane64 = tid & 63;
    int wv = (tid >> 6) & 1;
    float pm = 0.f;
    if (p0) {
        float lfa = ws[OFF_LFACC + bh * Tt + c * Ss + tid];
        float bt = ig[bh * Tt + c * Ss + tid] - lfa;
        sbt[tid] = bt;
        slfa[tid] = lfa;
        snp[tid] = nprev[tid];
        pm = bt;
        for (int off = 1; off < 64; off <<= 1) {
            float o = __shfl_up(pm, off);
            if (lane64 >= off) pm = fmaxf(pm, o);
        }
        if (lane64 == 63) scomb[wv] = pm;
    }
    __syncthreads();   // barrier A: images in LDS, sbt/slfa/snp/scomb ready

    if (p0) {
        if (wv == 1) pm = fmaxf(pm, scomb[0]);
        float mx = fmaxf(pm, m_prev);
        sas[tid] = -mx;
        siw[tid] = SCALE * __expf(m_prev - mx);
    }
    // intern raw dot: q[s].n_prev, s = S0+l15
    float dotq = 0.f;
#pragma unroll
    for (int kk = 0; kk < 4; kk++)
#pragma unroll
        for (int e = 0; e < 8; e++)
            dotq += (float)qf[kk][e] * snp[kk * 32 + g * 8 + e];
    dotq += __shfl_xor(dotq, 16);
    dotq += __shfl_xor(dotq, 32);
    __syncthreads();   // barrier B: sas/siw ready

    const float as_s = sas[S0 + l15];
    const float iw_s = siw[S0 + l15];
    const float lfa_s = slfa[S0 + l15];

    // ---- swapped QK^T: lane gets P[s=S0+l15][t=16tj+4g+r] ----
    unsigned plo[8] = {0,0,0,0,0,0,0,0};
    unsigned phi[8] = {0,0,0,0,0,0,0,0};
    float rs = 0.f;
#pragma unroll
    for (int tj = 0; tj < 8; tj++) {
        if (tj <= w) {
            int trow = tj * 16 + l15;
            f16x8 bfr[4];
#pragma unroll
            for (int kk = 0; kk < 4; kk++)
                bfr[kk] = *(const f16x8*)&XbK[trow * Kk + ((kk * 32 + g * 8) ^ swt)];
            f32x4 acc = {0.f, 0.f, 0.f, 0.f};
#pragma unroll
            for (int kk = 0; kk < 4; kk++)
                acc = __builtin_amdgcn_mfma_f32_16x16x32_f16(bfr[kk], qf[kk], acc, 0, 0, 0);
            float vals[4];
#pragma unroll
            for (int r = 0; r < 4; r++) {
                int t = tj * 16 + 4 * g + r;
                float btv = sbt[t];
                float val = acc[r] * SCALE * __expf(as_s + btv);
                if (tj == w && (4 * g + r) > l15) val = 0.f;   // causal mask
                rs += val;
                vals[r] = val;
            }
            U2 lo, hi;
            lo.h = (f16x2){ (_Float16)vals[0], (_Float16)vals[1] };
            hi.h = (f16x2){ (_Float16)vals[2], (_Float16)vals[3] };
            plo[tj] = lo.u;
            phi[tj] = hi.u;
        }
    }
    // full row sum + M_norm, all in registers
    rs += __shfl_xor(rs, 16);
    rs += __shfl_xor(rs, 32);
    float engs = __expf(as_s - lfa_s);              // exp(-(lfa+mx))
    float rnv_s = 1.0f / fmaxf(fabsf(rs + dotq * iw_s), engs);
    __syncthreads();   // barrier C: all QK^T reads of XbK done

    // ---- stage c_prev^T into XbK space (async; hidden under pb + PV) ----
#pragma unroll
    for (int p = 0; p < 4; p++) {
        int u = w * 4 + p;                           // wave-uniform
        GLDS16(cprevT + (size_t)(u * 64 + lane) * 8, &XbK[u * 512]);
    }

    // ---- P -> B-operand fragments via cross-g shfl exchange ----
    f16x8 pb[4];
    const int kmax = w >> 1;
    {
        int a2 = (g & 1) * 2;
        int sA = a2 * 16 + l15;
        int sB = sA + 16;
        bool hi2 = (g >> 1) != 0;
#pragma unroll
        for (int kkt = 0; kkt < 4; kkt++) {
            if (kkt <= kmax) {
                unsigned xA0 = __shfl((int)plo[2*kkt],   sA);
                unsigned xA1 = __shfl((int)phi[2*kkt],   sA);
                unsigned xB0 = __shfl((int)plo[2*kkt],   sB);
                unsigned xB1 = __shfl((int)phi[2*kkt],   sB);
                unsigned yA0 = __shfl((int)plo[2*kkt+1], sA);
                unsigned yA1 = __shfl((int)phi[2*kkt+1], sA);
                unsigned yB0 = __shfl((int)plo[2*kkt+1], sB);
                unsigned yB1 = __shfl((int)phi[2*kkt+1], sB);
                U8 t;
                t.u[0] = hi2 ? yA0 : xA0;
                t.u[1] = hi2 ? yA1 : xA1;
                t.u[2] = hi2 ? yB0 : xB0;
                t.u[3] = hi2 ? yB1 : xB1;
                pb[kkt] = t.v;
            }
        }
    }

    // ---- PV for BOTH halves (reads XbV only; covers c_prev load latency) ----
    f32x4 h4[2][4];
#pragma unroll
    for (int half = 0; half < 2; half++)
#pragma unroll
        for (int j = 0; j < 4; j++) h4[half][j] = (f32x4){0.f, 0.f, 0.f, 0.f};

#pragma unroll
    for (int kkt = 0; kkt < 4; kkt++) {
        if (kkt <= kmax) {
#pragma unroll
            for (int half = 0; half < 2; half++)
#pragma unroll
                for (int j = 0; j < 4; j++) {
                    int vr = (half * 4 + j) * 16 + l15;
                    f16x8 av = *(const f16x8*)&XbV[vr * Ss + ((kkt * 32 + g * 8) ^ swt)];
                    h4[half][j] = __builtin_amdgcn_mfma_f32_16x16x32_f16(av, pb[kkt], h4[half][j], 0, 0, 0);
                }
        }
    }

    asm volatile("s_waitcnt vmcnt(0)" ::: "memory");
    __syncthreads();   // barrier D: c_prev^T staged in XbK

    // ---- inter (LDS, swizzled) + combine + float4 stores ----
#pragma unroll
    for (int half = 0; half < 2; half++)
#pragma unroll
        for (int j = 0; j < 4; j++) {
            int vr = (half * 4 + j) * 16 + l15;
            f32x4 tmp = {0.f, 0.f, 0.f, 0.f};
            int swv = (vr & 15) << 3;
#pragma unroll
            for (int kk = 0; kk < 4; kk++) {
                f16x8 bcf = *(const f16x8*)&XbK[vr * Kk + ((kk * 32 + g * 8) ^ swv)];
                tmp = __builtin_amdgcn_mfma_f32_16x16x32_f16(bcf, qf[kk], tmp, 0, 0, 0);
            }
            float4 o;
            o.x = (h4[half][j][0] + tmp[0] * iw_s) * rnv_s;
            o.y = (h4[half][j][1] + tmp[1] * iw_s) * rnv_s;
            o.z = (h4[half][j][2] + tmp[2] * iw_s) * rnv_s;
            o.w = (h4[half][j][3] + tmp[3] * iw_s) * rnv_s;
            *(float4*)&out[(rowbase + S0 + l15) * Vv + (half * 4 + j) * 16 + 4 * g] = o;
        }
}

// ---------------------------------------------------------------------------
extern "C" void kernel_launch(void* const* d_in, const int* in_sizes, int n_in,
                              void* d_out, int out_size, void* d_ws, size_t ws_size,
                              hipStream_t stream) {
    (void)in_sizes; (void)n_in; (void)out_size; (void)ws_size;
    const float* q  = (const float*)d_in[0];
    const float* k  = (const float*)d_in[1];
    const float* v  = (const float*)d_in[2];
    const float* ig = (const float*)d_in[3];
    const float* fg = (const float*)d_in[4];
    const float* C0 = (const float*)d_in[5];
    const float* n0 = (const float*)d_in[6];
    const float* m0 = (const float*)d_in[7];
    float* out = (float*)d_out;
    float* ws  = (float*)d_ws;

    k_kvg<<<BH * Cc, 512, 0, stream>>>(ig, fg, k, v, ws);
    k_scan_apply<<<(BH * Kk * Vv / 2 + BH * Kk) / 128, 128, 0, stream>>>(C0, n0, m0, ws);
    k_out_mfma<<<BH * Cc, 512, 0, stream>>>(q, ig, m0, ws, out);
}